// Round 9
// baseline (377.767 us; speedup 1.0000x reference)
//
#include <hip/hip_runtime.h>
#include <hip/hip_bf16.h>

typedef __hip_bfloat16 bf16;
typedef __bf16 bf16x8 __attribute__((ext_vector_type(8)));
typedef float f32x4 __attribute__((ext_vector_type(4)));

#define DD   512
#define NT   1536
#define NH   4
#define DHD  128
#define NBINS 100
#define MAXI 5
#define NL   3
#define RSQRT_DH 0.08838834764831845f   // 1/sqrt(128)

// ---- fp32 workspace layout (float offsets) ----
#define OFF_ATT    ((size_t)0)                        // attn_out N x D (fp32, head)
#define OFF_CTX    (OFF_ATT  + (size_t)NT*DD)        // fmha output ctx
#define OFF_H0     (OFF_CTX  + (size_t)NT*DD)        // N x 384 fp32
#define OFF_AARR   (OFF_H0   + (size_t)NT*384)
#define OFF_BARR   (OFF_AARR + (size_t)NH*NT)
#define OFF_AV     (OFF_BARR + (size_t)NH*NT)
#define OFF_BV     (OFF_AV   + (size_t)DD)
#define OFF_B2     (OFF_BV   + (size_t)DD)
#define OFF_SOFF   (OFF_B2   + (size_t)DD)
#define OFF_EOFF   (OFF_SOFF + (size_t)MAXI*NT)
#define OFF_POOL   (OFF_EOFF + (size_t)MAXI*NT)
#define OFF_SCAL   (OFF_POOL + (size_t)DD)
#define OFF_E      (OFF_SCAL + (size_t)64)           // bf16 E0 region NH*NT*NT
#define SC_START 0
#define SC_END   5
#define SC_DSDE  10
#define SC_CNT   20
// ---- bf16 pool (element offsets), starts after E ----
#define BF_BASE  (OFF_E + (size_t)NH*NT*NT/2)
#define BQKB   ((size_t)0)                   // [NT][1024] Q|K
#define BVT    (BQKB  + (size_t)NT*1024)     // [NH][128][NT]
#define BATT   (BVT   + (size_t)NH*128*NT)   // [NT][512]
#define BK2    (BATT  + (size_t)NT*512)
#define BQ0    (BK2   + (size_t)NT*512)
#define BM2    (BQ0   + (size_t)NT*512)      // [512][512]
#define BINW   (BM2   + (size_t)512*512)     // [1536][512]
#define BOUTW  (BINW  + (size_t)1536*512)    // [512][512]
#define BRW1   (BOUTW + (size_t)512*512)     // [384][512]
#define BRW2   (BRW1  + (size_t)384*512)     // [3][200][128]

__device__ __forceinline__ void cvt8(const float* s, bf16* d) {
    float4 f0 = *(const float4*)s, f1 = *(const float4*)(s + 4);
    union { uint4 u; unsigned short us[8]; } o;
    bf16 t;
    t = __float2bfloat16(f0.x); o.us[0] = *(unsigned short*)&t;
    t = __float2bfloat16(f0.y); o.us[1] = *(unsigned short*)&t;
    t = __float2bfloat16(f0.z); o.us[2] = *(unsigned short*)&t;
    t = __float2bfloat16(f0.w); o.us[3] = *(unsigned short*)&t;
    t = __float2bfloat16(f1.x); o.us[4] = *(unsigned short*)&t;
    t = __float2bfloat16(f1.y); o.us[5] = *(unsigned short*)&t;
    t = __float2bfloat16(f1.z); o.us[6] = *(unsigned short*)&t;
    t = __float2bfloat16(f1.w); o.us[7] = *(unsigned short*)&t;
    *(uint4*)d = o.u;
}

// -------------------------------------------------------------------------
// prologue: M2B GEMM (0-63) | uv (64-71) | pre (72) | weight converts (73-97)
__global__ __launch_bounds__(256) void k_misc(
    const float* __restrict__ tpos, const float* __restrict__ in_w,
    const float* __restrict__ in_b, const float* __restrict__ out_w,
    const float* __restrict__ ref_w1, const float* __restrict__ ref_w2,
    const float* __restrict__ qp_w, const float* __restrict__ qp_b, float* ws)
{
    __shared__ __bf16 As[64 * 40];
    __shared__ __bf16 Bs[64 * 40];
    __shared__ float smn[256], smx[256];
    bf16* bp = (bf16*)(ws + BF_BASE);
    int bx = blockIdx.x, tid = threadIdx.x;
    if (bx < 64) {
        int m0 = (bx >> 3) * 64, n0 = (bx & 7) * 64;
        int r = tid >> 2, quad = tid & 3;
        int w = tid >> 6, lane = tid & 63;
        int wm = (w & 1) * 32, wn = (w >> 1) * 32;
        int lr = lane & 15, lq = lane >> 4;
        f32x4 acc[2][2];
#pragma unroll
        for (int i = 0; i < 2; i++)
#pragma unroll
            for (int j = 0; j < 2; j++) acc[i][j] = (f32x4){0.f, 0.f, 0.f, 0.f};
        const float* arow = in_w + (size_t)(m0 + r) * DD + quad * 8;
        int kk = tid >> 3, g = tid & 7;
        for (int k0 = 0; k0 < DD; k0 += 32) {
            __bf16 ta[8] __attribute__((aligned(16)));
#pragma unroll
            for (int q = 0; q < 4; q++) {
                float2 f = *(const float2*)(arow + k0 + 2 * q);
                ta[2 * q] = (__bf16)f.x; ta[2 * q + 1] = (__bf16)f.y;
            }
            const float* bsrc = qp_w + (size_t)(k0 + kk) * 514 + n0 + g * 8;
            float4 b0 = *(const float4*)bsrc;
            float4 b1 = *(const float4*)(bsrc + 4);
            float bb[8] = {b0.x, b0.y, b0.z, b0.w, b1.x, b1.y, b1.z, b1.w};
            __syncthreads();
            *(bf16x8*)&As[r * 40 + quad * 8] = *(bf16x8*)ta;
#pragma unroll
            for (int q = 0; q < 8; q++) Bs[(g * 8 + q) * 40 + kk] = (__bf16)bb[q];
            __syncthreads();
            bf16x8 af[2], bfr[2];
#pragma unroll
            for (int i = 0; i < 2; i++) af[i] = *(bf16x8*)&As[(wm + i * 16 + lr) * 40 + lq * 8];
#pragma unroll
            for (int j = 0; j < 2; j++) bfr[j] = *(bf16x8*)&Bs[(wn + j * 16 + lr) * 40 + lq * 8];
#pragma unroll
            for (int i = 0; i < 2; i++)
#pragma unroll
                for (int j = 0; j < 2; j++)
                    acc[i][j] = __builtin_amdgcn_mfma_f32_16x16x32_bf16(af[i], bfr[j], acc[i][j], 0, 0, 0);
        }
        bf16* M2B = bp + BM2;
#pragma unroll
        for (int i = 0; i < 2; i++)
#pragma unroll
            for (int r4 = 0; r4 < 4; r4++) {
                int gm = m0 + wm + i * 16 + lq * 4 + r4;
#pragma unroll
                for (int j = 0; j < 2; j++)
                    M2B[(size_t)gm * 512 + n0 + wn + j * 16 + lr] = __float2bfloat16(acc[i][j][r4]);
            }
    } else if (bx < 72) {
        int w = tid >> 6, lane = tid & 63;
        float su8[8], sv8[8], sb8[8];
#pragma unroll
        for (int q = 0; q < 8; q++) {
            int c = lane * 8 + q;
            su8[q] = qp_w[(size_t)c * 514 + 512];
            sv8[q] = qp_w[(size_t)c * 514 + 513];
            sb8[q] = qp_b[c];
        }
        int base = (bx - 64) * 64 + w * 16;
        for (int t = 0; t < 16; t++) {
            int row = base + t;
            const float* wr = in_w + (size_t)row * DD + lane * 8;
            float4 x0 = *(const float4*)wr, x1 = *(const float4*)(wr + 4);
            float xa[8] = {x0.x, x0.y, x0.z, x0.w, x1.x, x1.y, x1.z, x1.w};
            float a = 0.f, b = 0.f, c2 = 0.f;
#pragma unroll
            for (int q = 0; q < 8; q++) { a += xa[q] * su8[q]; b += xa[q] * sv8[q]; c2 += xa[q] * sb8[q]; }
            for (int off = 32; off; off >>= 1) {
                a += __shfl_xor(a, off); b += __shfl_xor(b, off); c2 += __shfl_xor(c2, off);
            }
            if (lane == 0) {
                ws[OFF_AV + row] = a; ws[OFF_BV + row] = b; ws[OFF_B2 + row] = c2 + in_b[row];
            }
        }
    } else if (bx == 72) {
        ws[OFF_POOL + tid] = 0.f; ws[OFF_POOL + 256 + tid] = 0.f;
        float mn = 1e30f, mx = -1e30f;
        for (int i = tid; i < NT; i += 256) { float v = tpos[i]; mn = fminf(mn, v); mx = fmaxf(mx, v); }
        smn[tid] = mn; smx[tid] = mx; __syncthreads();
        for (int s = 128; s; s >>= 1) {
            if (tid < s) { smn[tid] = fminf(smn[tid], smn[tid + s]); smx[tid] = fmaxf(smx[tid], smx[tid + s]); }
            __syncthreads();
        }
        if (tid == 0) {
            float tmin = smn[0], tmax = smx[0];
            for (int i = 0; i < MAXI; i++) {
                ws[OFF_SCAL + SC_START + i] = tmin + (tmax - tmin) * (float)i / 5.0f;
                ws[OFF_SCAL + SC_END + i]   = tmin + (tmax - tmin) * (float)(i + 1) / 5.0f;
            }
        }
    } else if (bx < 89) {
        size_t start = (size_t)(bx - 73) * 6144;
        for (int it = 0; it < 24; it++) {
            size_t g = start + it * 256 + tid;
            cvt8(in_w + g * 8, bp + BINW + g * 8);
        }
    } else if (bx < 93) {
        size_t start = (size_t)(bx - 89) * 8192;
        for (int it = 0; it < 32; it++) {
            size_t g = start + it * 256 + tid;
            cvt8(out_w + g * 8, bp + BOUTW + g * 8);
        }
    } else if (bx < 97) {
        size_t start = (size_t)(bx - 93) * 6144;
        for (int it = 0; it < 24; it++) {
            size_t g = start + it * 256 + tid;
            int row = (int)(g >> 6), col = (int)(g & 63) * 8;
            const float* s = ref_w1 + (size_t)row * 514 + col;
            float buf[8];
#pragma unroll
            for (int q = 0; q < 4; q++) { float2 f = *(const float2*)(s + 2 * q); buf[2 * q] = f.x; buf[2 * q + 1] = f.y; }
            cvt8(buf, bp + BRW1 + (size_t)row * 512 + col);
        }
    } else {
        for (int it = 0; it < 38; it++) {
            size_t g = (size_t)it * 256 + tid;
            if (g < 9600) cvt8(ref_w2 + g * 8, bp + BRW2 + g * 8);
        }
    }
}

// qkv = (emb + t*wt + bt) @ in_w^T + in_b -> QKB bf16 (Q|K), VtB bf16 transposed
__global__ __launch_bounds__(256) void k_qkv(
    const float* __restrict__ emb, const float* __restrict__ t,
    const float* __restrict__ wt, const float* __restrict__ bt,
    const float* __restrict__ in_b, float* ws)
{
    bf16* bp = (bf16*)(ws + BF_BASE);
    int m0 = blockIdx.y * 64, n0 = blockIdx.x * 64;
    __shared__ __bf16 As[64 * 40];
    __shared__ __bf16 Bs[64 * 40];
    int tid = threadIdx.x;
    int r = tid >> 2, quad = tid & 3;
    int w = tid >> 6, lane = tid & 63;
    int wm = (w & 1) * 32, wn = (w >> 1) * 32;
    int lr = lane & 15, lq = lane >> 4;
    f32x4 acc[2][2];
#pragma unroll
    for (int i = 0; i < 2; i++)
#pragma unroll
        for (int j = 0; j < 2; j++) acc[i][j] = (f32x4){0.f, 0.f, 0.f, 0.f};

    float trow = t[m0 + r];
    const float* arow = emb + (size_t)(m0 + r) * DD + quad * 8;
    const __bf16* brow = (const __bf16*)(bp + BINW) + (size_t)(n0 + r) * 512 + quad * 8;
    __bf16* awr = &As[r * 40 + quad * 8];
    __bf16* bwr = &Bs[r * 40 + quad * 8];

    for (int k0 = 0; k0 < DD; k0 += 32) {
        __bf16 ta[8] __attribute__((aligned(16)));
#pragma unroll
        for (int q = 0; q < 4; q++) {
            float2 e = *(const float2*)(arow + k0 + 2 * q);
            float2 wv = *(const float2*)(wt + k0 + quad * 8 + 2 * q);
            float2 bv = *(const float2*)(bt + k0 + quad * 8 + 2 * q);
            ta[2 * q]     = (__bf16)(e.x + trow * wv.x + bv.x);
            ta[2 * q + 1] = (__bf16)(e.y + trow * wv.y + bv.y);
        }
        uint4 bbv = *(const uint4*)(brow + k0);
        __syncthreads();
        *(bf16x8*)awr = *(bf16x8*)ta;
        *(uint4*)bwr = bbv;
        __syncthreads();
        bf16x8 af[2], bfr[2];
#pragma unroll
        for (int i = 0; i < 2; i++) af[i] = *(bf16x8*)&As[(wm + i * 16 + lr) * 40 + lq * 8];
#pragma unroll
        for (int j = 0; j < 2; j++) bfr[j] = *(bf16x8*)&Bs[(wn + j * 16 + lr) * 40 + lq * 8];
#pragma unroll
        for (int i = 0; i < 2; i++)
#pragma unroll
            for (int j = 0; j < 2; j++)
                acc[i][j] = __builtin_amdgcn_mfma_f32_16x16x32_bf16(af[i], bfr[j], acc[i][j], 0, 0, 0);
    }
    bf16* QKB = bp + BQKB;
    bf16* VtB = bp + BVT;
#pragma unroll
    for (int i = 0; i < 2; i++)
#pragma unroll
        for (int j = 0; j < 2; j++) {
            int gn = n0 + wn + j * 16 + lr;
            int gmb = m0 + wm + i * 16 + lq * 4;
            float b = in_b[gn];
            if (gn < 2 * DD) {
#pragma unroll
                for (int r4 = 0; r4 < 4; r4++)
                    QKB[(size_t)(gmb + r4) * 1024 + gn] = __float2bfloat16(acc[i][j][r4] + b);
            } else {
                union { uint2 u; unsigned short us[4]; } o;
#pragma unroll
                for (int r4 = 0; r4 < 4; r4++) {
                    bf16 t2 = __float2bfloat16(acc[i][j][r4] + b);
                    o.us[r4] = *(unsigned short*)&t2;
                }
                *(uint2*)&VtB[(size_t)(gn - 2 * DD) * NT + gmb] = o.u;
            }
        }
}

// fused flash MHA1: per (m-tile 64, head): QK^T -> exp -> PV, unshifted exp, den accumulated.
// grid (24, 4)
__global__ __launch_bounds__(256) void k_fmha(float* ws) {
    bf16* bp = (bf16*)(ws + BF_BASE);
    int h = blockIdx.y;
    int m0 = blockIdx.x * 64;
    __shared__ __bf16 Ks[64 * 136];
    __shared__ __bf16 Vs[128 * 72];
    __shared__ __bf16 Es[64 * 72];
    int tid = threadIdx.x;
    int w = tid >> 6, lane = tid & 63;
    int lr = lane & 15, lq = lane >> 4;
    int wm = w * 16;
    int r = tid >> 2, quad = tid & 3;
    const __bf16* QK = (const __bf16*)(bp + BQKB);
    // stage Q tile into Ks
    {
        const __bf16* qrow = QK + (size_t)(m0 + r) * 1024 + h * 128 + quad * 32;
        uint4 q0 = *(const uint4*)qrow;
        uint4 q1 = *(const uint4*)(qrow + 8);
        uint4 q2 = *(const uint4*)(qrow + 16);
        uint4 q3 = *(const uint4*)(qrow + 24);
        __bf16* d = &Ks[r * 136 + quad * 32];
        *(uint4*)d = q0; *(uint4*)(d + 8) = q1; *(uint4*)(d + 16) = q2; *(uint4*)(d + 24) = q3;
    }
    __syncthreads();
    bf16x8 afq[4];
#pragma unroll
    for (int ks = 0; ks < 4; ks++) afq[ks] = *(bf16x8*)&Ks[(wm + lr) * 136 + ks * 32 + lq * 8];
    f32x4 accO[8];
#pragma unroll
    for (int j = 0; j < 8; j++) accO[j] = (f32x4){0.f, 0.f, 0.f, 0.f};
    f32x4 den = (f32x4){0.f, 0.f, 0.f, 0.f};
    const __bf16* Vt = (const __bf16*)(bp + BVT) + (size_t)h * 128 * NT;
    int rB = tid >> 1, hhB = tid & 1;

    for (int kb = 0; kb < NT; kb += 64) {
        const __bf16* krow = QK + (size_t)(kb + r) * 1024 + 512 + h * 128 + quad * 32;
        uint4 k0v = *(const uint4*)krow;
        uint4 k1v = *(const uint4*)(krow + 8);
        uint4 k2v = *(const uint4*)(krow + 16);
        uint4 k3v = *(const uint4*)(krow + 24);
        const __bf16* vrow = Vt + (size_t)rB * NT + kb + hhB * 32;
        uint4 v0 = *(const uint4*)vrow;
        uint4 v1 = *(const uint4*)(vrow + 8);
        uint4 v2 = *(const uint4*)(vrow + 16);
        uint4 v3 = *(const uint4*)(vrow + 24);
        __syncthreads();   // previous iteration's LDS reads complete
        {
            __bf16* d = &Ks[r * 136 + quad * 32];
            *(uint4*)d = k0v; *(uint4*)(d + 8) = k1v; *(uint4*)(d + 16) = k2v; *(uint4*)(d + 24) = k3v;
            __bf16* dv = &Vs[rB * 72 + hhB * 32];
            *(uint4*)dv = v0; *(uint4*)(dv + 8) = v1; *(uint4*)(dv + 16) = v2; *(uint4*)(dv + 24) = v3;
        }
        __syncthreads();
        f32x4 accS[4];
#pragma unroll
        for (int j = 0; j < 4; j++) accS[j] = (f32x4){0.f, 0.f, 0.f, 0.f};
#pragma unroll
        for (int ks = 0; ks < 4; ks++) {
#pragma unroll
            for (int j = 0; j < 4; j++) {
                bf16x8 bk = *(bf16x8*)&Ks[(j * 16 + lr) * 136 + ks * 32 + lq * 8];
                accS[j] = __builtin_amdgcn_mfma_f32_16x16x32_bf16(afq[ks], bk, accS[j], 0, 0, 0);
            }
        }
        // exp + den + wave-private E tile (rows wm..wm+15)
#pragma unroll
        for (int j = 0; j < 4; j++) {
#pragma unroll
            for (int reg = 0; reg < 4; reg++) {
                float e = __expf(accS[j][reg] * RSQRT_DH);
                den[reg] += e;
                Es[(wm + lq * 4 + reg) * 72 + j * 16 + lr] = (__bf16)e;
            }
        }
        // PV (each wave reads only its own Es rows; same-wave LDS ordering via lgkmcnt)
#pragma unroll
        for (int ks = 0; ks < 2; ks++) {
            bf16x8 ae = *(bf16x8*)&Es[(wm + lr) * 72 + ks * 32 + lq * 8];
#pragma unroll
            for (int jn = 0; jn < 8; jn++) {
                bf16x8 bv = *(bf16x8*)&Vs[(jn * 16 + lr) * 72 + ks * 32 + lq * 8];
                accO[jn] = __builtin_amdgcn_mfma_f32_16x16x32_bf16(ae, bv, accO[jn], 0, 0, 0);
            }
        }
    }
    for (int off = 1; off < 16; off <<= 1) {
        den[0] += __shfl_xor(den[0], off);
        den[1] += __shfl_xor(den[1], off);
        den[2] += __shfl_xor(den[2], off);
        den[3] += __shfl_xor(den[3], off);
    }
    f32x4 ri;
    ri[0] = 1.f / den[0]; ri[1] = 1.f / den[1]; ri[2] = 1.f / den[2]; ri[3] = 1.f / den[3];
    float* ctx = ws + OFF_CTX;
#pragma unroll
    for (int jn = 0; jn < 8; jn++)
#pragma unroll
        for (int reg = 0; reg < 4; reg++) {
            int gm = m0 + wm + lq * 4 + reg;
            ctx[(size_t)gm * DD + h * 128 + jn * 16 + lr] = accO[jn][reg] * ri[reg];
        }
}

// attn_out = ctx @ out_w^T + out_b -> att fp32 + attB bf16, + fused pooling
__global__ __launch_bounds__(256) void k_oproj(const float* __restrict__ out_b, float* ws) {
    bf16* bp = (bf16*)(ws + BF_BASE);
    int m0 = blockIdx.y * 64, n0 = blockIdx.x * 64;
    __shared__ __bf16 As[64 * 40];
    __shared__ __bf16 Bs[64 * 40];
    __shared__ float ps[64];
    int tid = threadIdx.x;
    int r = tid >> 2, quad = tid & 3;
    int w = tid >> 6, lane = tid & 63;
    int wm = (w & 1) * 32, wn = (w >> 1) * 32;
    int lr = lane & 15, lq = lane >> 4;
    f32x4 acc[2][2];
#pragma unroll
    for (int i = 0; i < 2; i++)
#pragma unroll
        for (int j = 0; j < 2; j++) acc[i][j] = (f32x4){0.f, 0.f, 0.f, 0.f};
    if (tid < 64) ps[tid] = 0.f;

    const float* a0 = ws + OFF_CTX + (size_t)(m0 + r) * DD + quad * 8;
    const __bf16* brow = (const __bf16*)(bp + BOUTW) + (size_t)(n0 + r) * 512 + quad * 8;
    __bf16* awr = &As[r * 40 + quad * 8];
    __bf16* bwr = &Bs[r * 40 + quad * 8];

    for (int k0 = 0; k0 < DD; k0 += 32) {
        __bf16 ta[8] __attribute__((aligned(16)));
#pragma unroll
        for (int q = 0; q < 4; q++) {
            float2 x = *(const float2*)(a0 + k0 + 2 * q);
            ta[2 * q] = (__bf16)x.x; ta[2 * q + 1] = (__bf16)x.y;
        }
        uint4 bbv = *(const uint4*)(brow + k0);
        __syncthreads();
        *(bf16x8*)awr = *(bf16x8*)ta;
        *(uint4*)bwr = bbv;
        __syncthreads();
        bf16x8 af[2], bfr[2];
#pragma unroll
        for (int i = 0; i < 2; i++) af[i] = *(bf16x8*)&As[(wm + i * 16 + lr) * 40 + lq * 8];
#pragma unroll
        for (int j = 0; j < 2; j++) bfr[j] = *(bf16x8*)&Bs[(wn + j * 16 + lr) * 40 + lq * 8];
#pragma unroll
        for (int i = 0; i < 2; i++)
#pragma unroll
            for (int j = 0; j < 2; j++)
                acc[i][j] = __builtin_amdgcn_mfma_f32_16x16x32_bf16(af[i], bfr[j], acc[i][j], 0, 0, 0);
    }
    float* att = ws + OFF_ATT;
    bf16* attB = bp + BATT;
#pragma unroll
    for (int j = 0; j < 2; j++) {
        int gn = n0 + wn + j * 16 + lr;
        float b = out_b[gn];
        float colsum = 0.f;
#pragma unroll
        for (int i = 0; i < 2; i++)
#pragma unroll
            for (int r4 = 0; r4 < 4; r4++) {
                int gm = m0 + wm + i * 16 + lq * 4 + r4;
                float v = acc[i][j][r4] + b;
                att[(size_t)gm * DD + gn] = v;
                attB[(size_t)gm * 512 + gn] = __float2bfloat16(v);
                colsum += v;
            }
        atomicAdd(&ps[wn + j * 16 + lr], colsum);
    }
    __syncthreads();
    if (tid < 64) atomicAdd(&ws[OFF_POOL + n0 + tid], ps[tid]);
}

// triple GEMM A=attB: K2B (0-7) | Q0B (8-15) | H0 fp32 (16-21) + head block (22)
__global__ __launch_bounds__(256) void k_trip(
    const float* __restrict__ in_b, const float* __restrict__ ref_b1,
    const float* __restrict__ icw1, const float* __restrict__ icb1,
    const float* __restrict__ icw2, const float* __restrict__ icb2,
    float* ws, float* out)
{
    bf16* bp = (bf16*)(ws + BF_BASE);
    __shared__ __bf16 As[64 * 40];
    __shared__ __bf16 Bs[64 * 40];
    __shared__ float h1[128];
    __shared__ float lg[MAXI];
    int bx = blockIdx.x, tid = threadIdx.x;
    if (bx == 22) {
        if (blockIdx.y != 0) return;
        int w = tid >> 6, lane = tid & 63;
        const float* pp = ws + OFF_POOL + lane * 8;
        float4 p0 = *(const float4*)pp, p1 = *(const float4*)(pp + 4);
        float p8[8] = {p0.x, p0.y, p0.z, p0.w, p1.x, p1.y, p1.z, p1.w};
        for (int t = 0; t < 32; t++) {
            int row = w * 32 + t;
            const float* wr = icw1 + (size_t)row * DD + lane * 8;
            float4 a = *(const float4*)wr, b = *(const float4*)(wr + 4);
            float d = a.x * p8[0] + a.y * p8[1] + a.z * p8[2] + a.w * p8[3]
                    + b.x * p8[4] + b.y * p8[5] + b.z * p8[6] + b.w * p8[7];
            for (int off = 32; off; off >>= 1) d += __shfl_xor(d, off);
            if (lane == 0) h1[row] = fmaxf(d * (1.0f / NT) + icb1[row], 0.f);
        }
        __syncthreads();
        if (tid < MAXI) {
            float s = icb2[tid];
            for (int j = 0; j < 128; j++) s += icw2[tid * 128 + j] * h1[j];
            lg[tid] = s;
        }
        __syncthreads();
        if (tid == 0) {
            int best = 0; float bv = lg[0];
            for (int m = 1; m < MAXI; m++) if (lg[m] > bv) { bv = lg[m]; best = m; }
            int ni = best + 1;
            for (int i = 0; i < MAXI; i++) out[10 + i] = (i < ni) ? 1.f : 0.f;
        }
        return;
    }
    const __bf16* B; const float* bias; int n0, mode;
    bf16* Cb = nullptr; float* Cf = nullptr;
    if (bx < 8)       { B = (const __bf16*)(bp + BINW) + (size_t)512 * 512; bias = in_b + DD;   Cb = bp + BK2; n0 = bx * 64; mode = 0; }
    else if (bx < 16) { B = (const __bf16*)(bp + BM2);                      bias = ws + OFF_B2; Cb = bp + BQ0; n0 = (bx - 8) * 64; mode = 0; }
    else              { B = (const __bf16*)(bp + BRW1);                     bias = ref_b1;      Cf = ws + OFF_H0; n0 = (bx - 16) * 64; mode = 1; }
    int m0 = blockIdx.y * 64;
    int r = tid >> 2, quad = tid & 3;
    int w = tid >> 6, lane = tid & 63;
    int wm = (w & 1) * 32, wn = (w >> 1) * 32;
    int lr = lane & 15, lq = lane >> 4;
    f32x4 acc[2][2];
#pragma unroll
    for (int i = 0; i < 2; i++)
#pragma unroll
        for (int j = 0; j < 2; j++) acc[i][j] = (f32x4){0.f, 0.f, 0.f, 0.f};

    const __bf16* arow = (const __bf16*)(bp + BATT) + (size_t)(m0 + r) * 512 + quad * 8;
    const __bf16* brow = B + (size_t)(n0 + r) * 512 + quad * 8;
    __bf16* awr = &As[r * 40 + quad * 8];
    __bf16* bwr = &Bs[r * 40 + quad * 8];

    for (int k0 = 0; k0 < DD; k0 += 32) {
        uint4 av = *(const uint4*)(arow + k0);
        uint4 bv = *(const uint4*)(brow + k0);
        __syncthreads();
        *(uint4*)awr = av;
        *(uint4*)bwr = bv;
        __syncthreads();
        bf16x8 af[2], bfr[2];
#pragma unroll
        for (int i = 0; i < 2; i++) af[i] = *(bf16x8*)&As[(wm + i * 16 + lr) * 40 + lq * 8];
#pragma unroll
        for (int j = 0; j < 2; j++) bfr[j] = *(bf16x8*)&Bs[(wn + j * 16 + lr) * 40 + lq * 8];
#pragma unroll
        for (int i = 0; i < 2; i++)
#pragma unroll
            for (int j = 0; j < 2; j++)
                acc[i][j] = __builtin_amdgcn_mfma_f32_16x16x32_bf16(af[i], bfr[j], acc[i][j], 0, 0, 0);
    }
#pragma unroll
    for (int i = 0; i < 2; i++)
#pragma unroll
        for (int r4 = 0; r4 < 4; r4++) {
            int gm = m0 + wm + i * 16 + lq * 4 + r4;
#pragma unroll
            for (int j = 0; j < 2; j++) {
                int gn = n0 + wn + j * 16 + lr;
                float v = acc[i][j][r4] + bias[gn];
                if (mode == 0) Cb[(size_t)gm * 512 + gn] = __float2bfloat16(v);
                else           Cf[(size_t)gm * 384 + gn] = v;
            }
        }
}

// E0 = exp(Q0 K2^T / sqrt(dh)) (z<4) | abc: A/B dots from K2B (z==4)
__global__ __launch_bounds__(256) void k_score(
    const bf16* __restrict__ Ab, int lda, int aZ,
    const bf16* __restrict__ Bb, int ldb, int bZ,
    bf16* __restrict__ E, float* ws)
{
    int tid = threadIdx.x;
    if (blockIdx.z == 4) {
        bf16* bp = (bf16*)(ws + BF_BASE);
        int flat = blockIdx.y * 12 + blockIdx.x;
        int w = tid >> 6, lane = tid & 63;
        for (int t = w; t < 43; t += 4) {
            int row = flat * 43 + t;
            if (row >= NH * NT) break;
            int hh = row / NT, n = row % NT;
            const unsigned short* k2 = (const unsigned short*)(bp + BK2 + (size_t)n * 512 + hh * DHD);
            const float* av = ws + OFF_AV + hh * DHD;
            const float* bv = ws + OFF_BV + hh * DHD;
            int d = lane * 2;
            float k0 = __uint_as_float((unsigned)k2[d] << 16);
            float k1 = __uint_as_float((unsigned)k2[d + 1] << 16);
            float a = av[d] * k0 + av[d + 1] * k1;
            float b = bv[d] * k0 + bv[d + 1] * k1;
            for (int off = 32; off; off >>= 1) { a += __shfl_xor(a, off); b += __shfl_xor(b, off); }
            if (lane == 0) { ws[OFF_AARR + row] = a * RSQRT_DH; ws[OFF_BARR + row] = b * RSQRT_DH; }
        }
        return;
    }
    int z = blockIdx.z;
    const __bf16* A = (const __bf16*)Ab + (size_t)z * aZ;
    const __bf16* B = (const __bf16*)Bb + (size_t)z * bZ;
    int m0 = blockIdx.y * 128, n0 = blockIdx.x * 128;
    __shared__ __bf16 As[128 * 40];
    __shared__ __bf16 Bs[128 * 40];
    int r = tid >> 1, hh = tid & 1;
    int w = tid >> 6, lane = tid & 63;
    int wm = (w & 1) * 64, wn = (w >> 1) * 64;
    int lr = lane & 15, lq = lane >> 4;
    f32x4 acc[4][4];
#pragma unroll
    for (int i = 0; i < 4; i++)
#pragma unroll
        for (int j = 0; j < 4; j++) acc[i][j] = (f32x4){0.f, 0.f, 0.f, 0.f};

    const __bf16* arow = A + (size_t)(m0 + r) * lda + hh * 16;
    const __bf16* brow = B + (size_t)(n0 + r) * ldb + hh * 16;
    __bf16* awr = &As[r * 40 + hh * 16];
    __bf16* bwr = &Bs[r * 40 + hh * 16];

    for (int k0 = 0; k0 < DHD; k0 += 32) {
        uint4 a0 = *(const uint4*)(arow + k0);
        uint4 a1 = *(const uint4*)(arow + k0 + 8);
        uint4 b0 = *(const uint4*)(brow + k0);
        uint4 b1 = *(const uint4*)(brow + k0 + 8);
        __syncthreads();
        *(uint4*)awr = a0; *(uint4*)(awr + 8) = a1;
        *(uint4*)bwr = b0; *(uint4*)(bwr + 8) = b1;
        __syncthreads();
        bf16x8 af[4], bfr[4];
#pragma unroll
        for (int i = 0; i < 4; i++) af[i] = *(bf16x8*)&As[(wm + i * 16 + lr) * 40 + lq * 8];
#pragma unroll
        for (int j = 0; j < 4; j++) bfr[j] = *(bf16x8*)&Bs[(wn + j * 16 + lr) * 40 + lq * 8];
#pragma unroll
        for (int i = 0; i < 4; i++)
#pragma unroll
            for (int j = 0; j < 4; j++)
                acc[i][j] = __builtin_amdgcn_mfma_f32_16x16x32_bf16(af[i], bfr[j], acc[i][j], 0, 0, 0);
    }
    bf16* Ez = E + (size_t)z * NT * NT;
#pragma unroll
    for (int i = 0; i < 4; i++)
#pragma unroll
        for (int r4 = 0; r4 < 4; r4++) {
            int gm = m0 + wm + i * 16 + lq * 4 + r4;
#pragma unroll
            for (int j = 0; j < 4; j++) {
                float e = __expf(acc[i][j][r4] * RSQRT_DH);
                Ez[(size_t)gm * NT + n0 + wn + j * 16 + lr] = __float2bfloat16(e);
            }
        }
}

// fused: logits = relu(H0+delta)@rw2B^T + b2 in LDS, then softdot -> so/eo
__global__ __launch_bounds__(256) void k_lgs(
    const float* __restrict__ rw1, const float* __restrict__ rb2,
    const float* __restrict__ wp, int l, float* ws)
{
    bf16* bp = (bf16*)(ws + BF_BASE);
    __shared__ float dsh[128];
    __shared__ __bf16 As[64 * 136];
    __shared__ __bf16 Bs[64 * 136];
    __shared__ __bf16 Ls[64 * 208];
    int tid = threadIdx.x;
    int m0 = blockIdx.x * 64;
    int i_int = m0 / NT;
    int nbase = m0 % NT;
    if (blockIdx.x == 0 && tid < 11) ws[OFF_SCAL + SC_DSDE + tid] = 0.f;   // dsde[10] + ticket
    if (tid < 128) {
        float s_i = ws[OFF_SCAL + SC_START + i_int], e_i = ws[OFF_SCAL + SC_END + i_int];
        const float* wr = rw1 + (size_t)(l * 128 + tid) * 514;
        dsh[tid] = s_i * wr[512] + e_i * wr[513];
    }
    __syncthreads();
    int r = tid >> 2, quad = tid & 3;
    {
        const float* arow = ws + OFF_H0 + (size_t)(nbase + r) * 384 + l * 128 + quad * 32;
        __bf16 tmp[32] __attribute__((aligned(16)));
#pragma unroll
        for (int q = 0; q < 16; q++) {
            float2 f = *(const float2*)(arow + 2 * q);
            int jj = quad * 32 + 2 * q;
            tmp[2 * q]     = (__bf16)fmaxf(f.x + dsh[jj], 0.f);
            tmp[2 * q + 1] = (__bf16)fmaxf(f.y + dsh[jj + 1], 0.f);
        }
        __bf16* aw = &As[r * 136 + quad * 32];
#pragma unroll
        for (int q = 0; q < 4; q++) *(bf16x8*)(aw + q * 8) = *(bf16x8*)(tmp + q * 8);
    }
    int w = tid >> 6, lane = tid & 63;
    int wm = (w & 1) * 32, wn = (w >> 1) * 32;
    int lr = lane & 15, lq = lane >> 4;
    const __bf16* rw2b = (const __bf16*)(bp + BRW2) + (size_t)l * 200 * 128;
    for (int nt = 0; nt < 4; nt++) {
        int n0 = nt * 64;
        int gnr = n0 + r;
        uint4 b0 = {0, 0, 0, 0}, b1 = {0, 0, 0, 0}, b2v = {0, 0, 0, 0}, b3 = {0, 0, 0, 0};
        if (gnr < 200) {
            const __bf16* brow = rw2b + (size_t)gnr * 128 + quad * 32;
            b0 = *(const uint4*)brow; b1 = *(const uint4*)(brow + 8);
            b2v = *(const uint4*)(brow + 16); b3 = *(const uint4*)(brow + 24);
        }
        __syncthreads();
        {
            __bf16* bw = &Bs[r * 136 + quad * 32];
            *(uint4*)bw = b0; *(uint4*)(bw + 8) = b1;
            *(uint4*)(bw + 16) = b2v; *(uint4*)(bw + 24) = b3;
        }
        __syncthreads();
        f32x4 acc[2][2];
#pragma unroll
        for (int i = 0; i < 2; i++)
#pragma unroll
            for (int j = 0; j < 2; j++) acc[i][j] = (f32x4){0.f, 0.f, 0.f, 0.f};
#pragma unroll
        for (int kk = 0; kk < 4; kk++) {
            bf16x8 af[2], bfr[2];
#pragma unroll
            for (int i = 0; i < 2; i++) af[i] = *(bf16x8*)&As[(wm + i * 16 + lr) * 136 + kk * 32 + lq * 8];
#pragma unroll
            for (int j = 0; j < 2; j++) bfr[j] = *(bf16x8*)&Bs[(wn + j * 16 + lr) * 136 + kk * 32 + lq * 8];
#pragma unroll
            for (int i = 0; i < 2; i++)
#pragma unroll
                for (int j = 0; j < 2; j++)
                    acc[i][j] = __builtin_amdgcn_mfma_f32_16x16x32_bf16(af[i], bfr[j], acc[i][j], 0, 0, 0);
        }
#pragma unroll
        for (int i = 0; i < 2; i++)
#pragma unroll
            for (int r4 = 0; r4 < 4; r4++) {
                int rl = wm + i * 16 + lq * 4 + r4;
#pragma unroll
                for (int j = 0; j < 2; j++) {
                    int gn = n0 + wn + j * 16 + lr;
                    if (gn < 200) Ls[rl * 208 + gn] = (__bf16)(acc[i][j][r4] + rb2[gn]);
                }
            }
    }
    __syncthreads();
    {
        int rloc = tid >> 2, q = tid & 3;
        int c0 = q * 50;
        const unsigned short* lrow = (const unsigned short*)&Ls[rloc * 208];
        float m = -1e30f;
#pragma unroll
        for (int c = 0; c < 50; c++)
            m = fmaxf(m, __uint_as_float((unsigned)lrow[c0 + c] << 16));
        m = fmaxf(m, __shfl_xor(m, 1));
        float den = 0.f, num = 0.f;
#pragma unroll
        for (int c = 0; c < 50; c++) {
            float p = __expf(__uint_as_float((unsigned)lrow[c0 + c] << 16) - m);
            den += p;
            int wc = c0 + c; if (wc >= NBINS) wc -= NBINS;
            num += p * wp[wc];
        }
        den += __shfl_xor(den, 1);
        num += __shfl_xor(num, 1);
        int n = nbase + rloc;
        if (q == 0)      ws[OFF_SOFF + (size_t)i_int * NT + n] = num / den;
        else if (q == 2) ws[OFF_EOFF + (size_t)i_int * NT + n] = num / den;
    }
}

// full-K: P = E0 @ U^T (U on-the-fly), in-block ratios + dsde atomics + ticket update
// grid (24, 4)
__global__ __launch_bounds__(256) void k_egf(const bf16* __restrict__ E0, float* ws, float* out, int l) {
    int h = blockIdx.y;
    int m0 = blockIdx.x * 64;
    __shared__ __bf16 As[64 * 72];
    __shared__ __bf16 Bs[16 * 72];
    __shared__ float Ps[64 * 17];
    int tid = threadIdx.x;
    int w = tid >> 6, lane = tid & 63;
    int lr = lane & 15, lq = lane >> 4;
    int wm = w * 16;
    int r = tid >> 2, quad = tid & 3;   // A: 64 rows x 16 elems each
    const unsigned short* arow =
        (const unsigned short*)((const __bf16*)E0 + (size_t)h * NT * NT + (size_t)(m0 + r) * NT) + quad * 16;
    f32x4 acc = (f32x4){0.f, 0.f, 0.f, 0.f};
    int bc = tid >> 4, bk = tid & 15;   // 16 cols (15 used) x 16 k-groups of 4
    int bvalid = (bc < 15);
    int ii = bc / 3, tt = bc - ii * 3;
    if (ii > 4) ii = 4;
    float s_i = ws[OFF_SCAL + SC_START + ii], e_i = ws[OFF_SCAL + SC_END + ii];
    const float* Ar = ws + OFF_AARR + h * NT;
    const float* Br = ws + OFF_BARR + h * NT;
    const float* fo = ws + (tt == 2 ? OFF_EOFF : OFF_SOFF) + (size_t)ii * NT;

    for (int k0 = 0; k0 < NT; k0 += 64) {
        uint4 a0 = *(const uint4*)(arow + k0);
        uint4 a1 = *(const uint4*)(arow + k0 + 8);
        float bv[4] = {0.f, 0.f, 0.f, 0.f};
        if (bvalid) {
            float4 a4 = *(const float4*)(Ar + k0 + bk * 4);
            float4 b4 = *(const float4*)(Br + k0 + bk * 4);
            bv[0] = __expf(s_i * a4.x + e_i * b4.x);
            bv[1] = __expf(s_i * a4.y + e_i * b4.y);
            bv[2] = __expf(s_i * a4.z + e_i * b4.z);
            bv[3] = __expf(s_i * a4.w + e_i * b4.w);
            if (tt) {
                float4 f4 = *(const float4*)(fo + k0 + bk * 4);
                bv[0] *= f4.x; bv[1] *= f4.y; bv[2] *= f4.z; bv[3] *= f4.w;
            }
        }
        __syncthreads();
        *(uint4*)&As[r * 72 + quad * 16] = a0;
        *(uint4*)&As[r * 72 + quad * 16 + 8] = a1;
        if (bvalid) {
            __bf16* bw = &Bs[bc * 72 + bk * 4];
            bw[0] = (__bf16)bv[0]; bw[1] = (__bf16)bv[1]; bw[2] = (__bf16)bv[2]; bw[3] = (__bf16)bv[3];
        }
        __syncthreads();
#pragma unroll
        for (int ks = 0; ks < 2; ks++) {
            bf16x8 af = *(bf16x8*)&As[(wm + lr) * 72 + ks * 32 + lq * 8];
            bf16x8 bf0 = *(bf16x8*)&Bs[lr * 72 + ks * 32 + lq * 8];
            acc = __builtin_amdgcn_mfma_f32_16x16x32_bf16(af, bf0, acc, 0, 0, 0);
        }
    }
    // transpose tile to LDS: lane holds col=lr, rows wm+lq*4+reg
#pragma unroll
    for (int reg = 0; reg < 4; reg++)
        Ps[(wm + lq * 4 + reg) * 17 + lr] = acc[reg];
    __syncthreads();
    if (w == 0) {   // wave 0: lane = row
        const float* P = &Ps[lane * 17];
        float loc[10];
#pragma unroll
        for (int i = 0; i < MAXI; i++) {
            float dn = P[i * 3];
            loc[i]        = P[i * 3 + 1] / dn;
            loc[MAXI + i] = P[i * 3 + 2] / dn;
        }
#pragma unroll
        for (int c = 0; c < 10; c++)
            for (int off = 32; off; off >>= 1) loc[c] += __shfl_xor(loc[c], off);
        if (lane == 0) {
#pragma unroll
            for (int c = 0; c < 10; c++) atomicAdd(&ws[OFF_SCAL + SC_DSDE + c], loc[c]);
            __threadfence();
            unsigned old = atomicAdd((unsigned*)&ws[OFF_SCAL + SC_CNT], 1u);
            if (old == 95) {   // last of 96 blocks
                for (int i = 0; i < MAXI; i++) {
                    float ds = atomicAdd(&ws[OFF_SCAL + SC_DSDE + i], 0.f);
                    float de = atomicAdd(&ws[OFF_SCAL + SC_DSDE + MAXI + i], 0.f);
                    float ns = ws[OFF_SCAL + SC_START + i] + ds * 0.25f;   // 1/H
                    float ne = ws[OFF_SCAL + SC_END + i]   + de * 0.25f;
                    ws[OFF_SCAL + SC_START + i] = ns;
                    ws[OFF_SCAL + SC_END + i]   = ne;
                    if (l == NL - 1) { out[2 * i] = ns; out[2 * i + 1] = ne; }
                }
            }
        }
    }
}

// -------------------------------------------------------------------------
extern "C" void kernel_launch(void* const* d_in, const int* in_sizes, int n_in,
                              void* d_out, int out_size, void* d_ws, size_t ws_size,
                              hipStream_t stream) {
    const float* emb    = (const float*)d_in[0];
    const float* tpos   = (const float*)d_in[1];
    const float* W_time = (const float*)d_in[3];
    const float* b_time = (const float*)d_in[4];
    const float* in_w   = (const float*)d_in[5];
    const float* in_b   = (const float*)d_in[6];
    const float* out_w  = (const float*)d_in[7];
    const float* out_b  = (const float*)d_in[8];
    const float* ic_w1  = (const float*)d_in[9];
    const float* ic_b1  = (const float*)d_in[10];
    const float* ic_w2  = (const float*)d_in[11];
    const float* ic_b2  = (const float*)d_in[12];
    const float* ref_w1 = (const float*)d_in[13];
    const float* ref_b1 = (const float*)d_in[14];
    const float* ref_w2 = (const float*)d_in[15];
    const float* ref_b2 = (const float*)d_in[16];
    const float* wp     = (const float*)d_in[17];
    const float* qp_w   = (const float*)d_in[18];
    const float* qp_b   = (const float*)d_in[19];
    float* ws  = (float*)d_ws;
    float* out = (float*)d_out;
    bf16* E = (bf16*)(ws + OFF_E);
    bf16* bp = (bf16*)(ws + BF_BASE);

    // prologue: M2B | uv | pre | weight-to-bf16 converts
    k_misc<<<98, 256, 0, stream>>>(tpos, in_w, in_b, out_w, ref_w1, ref_w2, qp_w, qp_b, ws);

    // qkv (+x fusion) -> QKB bf16, VtB bf16
    k_qkv<<<dim3(24, 24), 256, 0, stream>>>(emb, tpos, W_time, b_time, in_b, ws);
    // fused flash MHA1 -> ctx
    k_fmha<<<dim3(24, NH), 256, 0, stream>>>(ws);
    k_oproj<<<dim3(8, 24), 256, 0, stream>>>(out_b, ws);

    // K2B | Q0B | H0 | head
    k_trip<<<dim3(23, 24), 256, 0, stream>>>(in_b, ref_b1, ic_w1, ic_b1, ic_w2, ic_b2, ws, out);

    // E0 = exp(Q0 K2^T / sqrt(dh)) + abc fold (z==4)
    k_score<<<dim3(12, 12, 5), 256, 0, stream>>>(
        bp + BQ0, 512, DHD, bp + BK2, 512, DHD, E, ws);

    for (int l = 0; l < NL; l++) {
        k_lgs<<<120, 256, 0, stream>>>(ref_w1, ref_b2 + l * 200, wp, l, ws);
        k_egf<<<dim3(24, NH), 256, 0, stream>>>(E, ws, out, l);
    }
}

// Round 10
// 352.815 us; speedup vs baseline: 1.0707x; 1.0707x over previous
//
#include <hip/hip_runtime.h>
#include <hip/hip_bf16.h>

typedef __hip_bfloat16 bf16;
typedef __bf16 bf16x8 __attribute__((ext_vector_type(8)));
typedef float f32x4 __attribute__((ext_vector_type(4)));

#define DD   512
#define NT   1536
#define NH   4
#define DHD  128
#define NBINS 100
#define MAXI 5
#define NL   3
#define RSQRT_DH 0.08838834764831845f   // 1/sqrt(128)

// ---- fp32 workspace layout (float offsets) ----
#define OFF_ATT    ((size_t)0)                        // attn_out N x D (fp32, head)
#define OFF_CTX    (OFF_ATT  + (size_t)NT*DD)        // pv partial ks=0
#define OFF_CTX1   (OFF_CTX  + (size_t)NT*DD)        // pv partial ks=1
#define OFF_H0     (OFF_CTX1 + (size_t)NT*DD)        // N x 384 fp32
#define OFF_AARR   (OFF_H0   + (size_t)NT*384)
#define OFF_BARR   (OFF_AARR + (size_t)NH*NT)
#define OFF_AV     (OFF_BARR + (size_t)NH*NT)
#define OFF_BV     (OFF_AV   + (size_t)DD)
#define OFF_B2     (OFF_BV   + (size_t)DD)
#define OFF_SOFF   (OFF_B2   + (size_t)DD)
#define OFF_EOFF   (OFF_SOFF + (size_t)MAXI*NT)
#define OFF_STAT   (OFF_EOFF + (size_t)MAXI*NT)      // [NH*NT][12] expsums (MHA1)
#define OFF_POOL   (OFF_STAT + (size_t)NH*NT*12)
#define OFF_SCAL   (OFF_POOL + (size_t)DD)
#define OFF_E      (OFF_SCAL + (size_t)64)           // bf16 E region NH*NT*NT
#define SC_START 0
#define SC_END   5
#define SC_DSDE  10
#define SC_CNT   20
// ---- bf16 pool (element offsets), starts after E ----
#define BF_BASE  (OFF_E + (size_t)NH*NT*NT/2)
#define BQKB   ((size_t)0)                   // [NT][1024] Q|K
#define BVT    (BQKB  + (size_t)NT*1024)     // [NH][128][NT]
#define BATT   (BVT   + (size_t)NH*128*NT)   // [NT][512]
#define BK2    (BATT  + (size_t)NT*512)
#define BQ0    (BK2   + (size_t)NT*512)
#define BM2    (BQ0   + (size_t)NT*512)      // [512][512]
#define BINW   (BM2   + (size_t)512*512)     // [1536][512]
#define BOUTW  (BINW  + (size_t)1536*512)    // [512][512]
#define BRW1   (BOUTW + (size_t)512*512)     // [384][512]
#define BRW2   (BRW1  + (size_t)384*512)     // [3][200][128]

__device__ __forceinline__ void cvt8(const float* s, bf16* d) {
    float4 f0 = *(const float4*)s, f1 = *(const float4*)(s + 4);
    union { uint4 u; unsigned short us[8]; } o;
    bf16 t;
    t = __float2bfloat16(f0.x); o.us[0] = *(unsigned short*)&t;
    t = __float2bfloat16(f0.y); o.us[1] = *(unsigned short*)&t;
    t = __float2bfloat16(f0.z); o.us[2] = *(unsigned short*)&t;
    t = __float2bfloat16(f0.w); o.us[3] = *(unsigned short*)&t;
    t = __float2bfloat16(f1.x); o.us[4] = *(unsigned short*)&t;
    t = __float2bfloat16(f1.y); o.us[5] = *(unsigned short*)&t;
    t = __float2bfloat16(f1.z); o.us[6] = *(unsigned short*)&t;
    t = __float2bfloat16(f1.w); o.us[7] = *(unsigned short*)&t;
    *(uint4*)d = o.u;
}

// -------------------------------------------------------------------------
// prologue: M2B GEMM (0-63) | uv (64-71) | pre (72) | weight converts (73-97)
__global__ __launch_bounds__(256) void k_misc(
    const float* __restrict__ tpos, const float* __restrict__ in_w,
    const float* __restrict__ in_b, const float* __restrict__ out_w,
    const float* __restrict__ ref_w1, const float* __restrict__ ref_w2,
    const float* __restrict__ qp_w, const float* __restrict__ qp_b, float* ws)
{
    __shared__ __bf16 As[64 * 40];
    __shared__ __bf16 Bs[64 * 40];
    __shared__ float smn[256], smx[256];
    bf16* bp = (bf16*)(ws + BF_BASE);
    int bx = blockIdx.x, tid = threadIdx.x;
    if (bx < 64) {
        int m0 = (bx >> 3) * 64, n0 = (bx & 7) * 64;
        int r = tid >> 2, quad = tid & 3;
        int w = tid >> 6, lane = tid & 63;
        int wm = (w & 1) * 32, wn = (w >> 1) * 32;
        int lr = lane & 15, lq = lane >> 4;
        f32x4 acc[2][2];
#pragma unroll
        for (int i = 0; i < 2; i++)
#pragma unroll
            for (int j = 0; j < 2; j++) acc[i][j] = (f32x4){0.f, 0.f, 0.f, 0.f};
        const float* arow = in_w + (size_t)(m0 + r) * DD + quad * 8;
        int kk = tid >> 3, g = tid & 7;
        for (int k0 = 0; k0 < DD; k0 += 32) {
            __bf16 ta[8] __attribute__((aligned(16)));
#pragma unroll
            for (int q = 0; q < 4; q++) {
                float2 f = *(const float2*)(arow + k0 + 2 * q);
                ta[2 * q] = (__bf16)f.x; ta[2 * q + 1] = (__bf16)f.y;
            }
            const float* bsrc = qp_w + (size_t)(k0 + kk) * 514 + n0 + g * 8;
            float4 b0 = *(const float4*)bsrc;
            float4 b1 = *(const float4*)(bsrc + 4);
            float bb[8] = {b0.x, b0.y, b0.z, b0.w, b1.x, b1.y, b1.z, b1.w};
            __syncthreads();
            *(bf16x8*)&As[r * 40 + quad * 8] = *(bf16x8*)ta;
#pragma unroll
            for (int q = 0; q < 8; q++) Bs[(g * 8 + q) * 40 + kk] = (__bf16)bb[q];
            __syncthreads();
            bf16x8 af[2], bfr[2];
#pragma unroll
            for (int i = 0; i < 2; i++) af[i] = *(bf16x8*)&As[(wm + i * 16 + lr) * 40 + lq * 8];
#pragma unroll
            for (int j = 0; j < 2; j++) bfr[j] = *(bf16x8*)&Bs[(wn + j * 16 + lr) * 40 + lq * 8];
#pragma unroll
            for (int i = 0; i < 2; i++)
#pragma unroll
                for (int j = 0; j < 2; j++)
                    acc[i][j] = __builtin_amdgcn_mfma_f32_16x16x32_bf16(af[i], bfr[j], acc[i][j], 0, 0, 0);
        }
        bf16* M2B = bp + BM2;
#pragma unroll
        for (int i = 0; i < 2; i++)
#pragma unroll
            for (int r4 = 0; r4 < 4; r4++) {
                int gm = m0 + wm + i * 16 + lq * 4 + r4;
#pragma unroll
                for (int j = 0; j < 2; j++)
                    M2B[(size_t)gm * 512 + n0 + wn + j * 16 + lr] = __float2bfloat16(acc[i][j][r4]);
            }
    } else if (bx < 72) {
        int w = tid >> 6, lane = tid & 63;
        float su8[8], sv8[8], sb8[8];
#pragma unroll
        for (int q = 0; q < 8; q++) {
            int c = lane * 8 + q;
            su8[q] = qp_w[(size_t)c * 514 + 512];
            sv8[q] = qp_w[(size_t)c * 514 + 513];
            sb8[q] = qp_b[c];
        }
        int base = (bx - 64) * 64 + w * 16;
        for (int t = 0; t < 16; t++) {
            int row = base + t;
            const float* wr = in_w + (size_t)row * DD + lane * 8;
            float4 x0 = *(const float4*)wr, x1 = *(const float4*)(wr + 4);
            float xa[8] = {x0.x, x0.y, x0.z, x0.w, x1.x, x1.y, x1.z, x1.w};
            float a = 0.f, b = 0.f, c2 = 0.f;
#pragma unroll
            for (int q = 0; q < 8; q++) { a += xa[q] * su8[q]; b += xa[q] * sv8[q]; c2 += xa[q] * sb8[q]; }
            for (int off = 32; off; off >>= 1) {
                a += __shfl_xor(a, off); b += __shfl_xor(b, off); c2 += __shfl_xor(c2, off);
            }
            if (lane == 0) {
                ws[OFF_AV + row] = a; ws[OFF_BV + row] = b; ws[OFF_B2 + row] = c2 + in_b[row];
            }
        }
    } else if (bx == 72) {
        ws[OFF_POOL + tid] = 0.f; ws[OFF_POOL + 256 + tid] = 0.f;
        float mn = 1e30f, mx = -1e30f;
        for (int i = tid; i < NT; i += 256) { float v = tpos[i]; mn = fminf(mn, v); mx = fmaxf(mx, v); }
        smn[tid] = mn; smx[tid] = mx; __syncthreads();
        for (int s = 128; s; s >>= 1) {
            if (tid < s) { smn[tid] = fminf(smn[tid], smn[tid + s]); smx[tid] = fmaxf(smx[tid], smx[tid + s]); }
            __syncthreads();
        }
        if (tid == 0) {
            float tmin = smn[0], tmax = smx[0];
            for (int i = 0; i < MAXI; i++) {
                ws[OFF_SCAL + SC_START + i] = tmin + (tmax - tmin) * (float)i / 5.0f;
                ws[OFF_SCAL + SC_END + i]   = tmin + (tmax - tmin) * (float)(i + 1) / 5.0f;
            }
        }
    } else if (bx < 89) {
        size_t start = (size_t)(bx - 73) * 6144;
        for (int it = 0; it < 24; it++) {
            size_t g = start + it * 256 + tid;
            cvt8(in_w + g * 8, bp + BINW + g * 8);
        }
    } else if (bx < 93) {
        size_t start = (size_t)(bx - 89) * 8192;
        for (int it = 0; it < 32; it++) {
            size_t g = start + it * 256 + tid;
            cvt8(out_w + g * 8, bp + BOUTW + g * 8);
        }
    } else if (bx < 97) {
        size_t start = (size_t)(bx - 93) * 6144;
        for (int it = 0; it < 24; it++) {
            size_t g = start + it * 256 + tid;
            int row = (int)(g >> 6), col = (int)(g & 63) * 8;
            const float* s = ref_w1 + (size_t)row * 514 + col;
            float buf[8];
#pragma unroll
            for (int q = 0; q < 4; q++) { float2 f = *(const float2*)(s + 2 * q); buf[2 * q] = f.x; buf[2 * q + 1] = f.y; }
            cvt8(buf, bp + BRW1 + (size_t)row * 512 + col);
        }
    } else {
        for (int it = 0; it < 38; it++) {
            size_t g = (size_t)it * 256 + tid;
            if (g < 9600) cvt8(ref_w2 + g * 8, bp + BRW2 + g * 8);
        }
    }
}

// qkv = (emb + t*wt + bt) @ in_w^T + in_b -> QKB bf16 (Q|K), VtB bf16 transposed
__global__ __launch_bounds__(256) void k_qkv(
    const float* __restrict__ emb, const float* __restrict__ t,
    const float* __restrict__ wt, const float* __restrict__ bt,
    const float* __restrict__ in_b, float* ws)
{
    bf16* bp = (bf16*)(ws + BF_BASE);
    int m0 = blockIdx.y * 64, n0 = blockIdx.x * 64;
    __shared__ __bf16 As[64 * 40];
    __shared__ __bf16 Bs[64 * 40];
    int tid = threadIdx.x;
    int r = tid >> 2, quad = tid & 3;
    int w = tid >> 6, lane = tid & 63;
    int wm = (w & 1) * 32, wn = (w >> 1) * 32;
    int lr = lane & 15, lq = lane >> 4;
    f32x4 acc[2][2];
#pragma unroll
    for (int i = 0; i < 2; i++)
#pragma unroll
        for (int j = 0; j < 2; j++) acc[i][j] = (f32x4){0.f, 0.f, 0.f, 0.f};

    float trow = t[m0 + r];
    const float* arow = emb + (size_t)(m0 + r) * DD + quad * 8;
    const __bf16* brow = (const __bf16*)(bp + BINW) + (size_t)(n0 + r) * 512 + quad * 8;
    __bf16* awr = &As[r * 40 + quad * 8];
    __bf16* bwr = &Bs[r * 40 + quad * 8];

    for (int k0 = 0; k0 < DD; k0 += 32) {
        __bf16 ta[8] __attribute__((aligned(16)));
#pragma unroll
        for (int q = 0; q < 4; q++) {
            float2 e = *(const float2*)(arow + k0 + 2 * q);
            float2 wv = *(const float2*)(wt + k0 + quad * 8 + 2 * q);
            float2 bv = *(const float2*)(bt + k0 + quad * 8 + 2 * q);
            ta[2 * q]     = (__bf16)(e.x + trow * wv.x + bv.x);
            ta[2 * q + 1] = (__bf16)(e.y + trow * wv.y + bv.y);
        }
        uint4 bbv = *(const uint4*)(brow + k0);
        __syncthreads();
        *(bf16x8*)awr = *(bf16x8*)ta;
        *(uint4*)bwr = bbv;
        __syncthreads();
        bf16x8 af[2], bfr[2];
#pragma unroll
        for (int i = 0; i < 2; i++) af[i] = *(bf16x8*)&As[(wm + i * 16 + lr) * 40 + lq * 8];
#pragma unroll
        for (int j = 0; j < 2; j++) bfr[j] = *(bf16x8*)&Bs[(wn + j * 16 + lr) * 40 + lq * 8];
#pragma unroll
        for (int i = 0; i < 2; i++)
#pragma unroll
            for (int j = 0; j < 2; j++)
                acc[i][j] = __builtin_amdgcn_mfma_f32_16x16x32_bf16(af[i], bfr[j], acc[i][j], 0, 0, 0);
    }
    bf16* QKB = bp + BQKB;
    bf16* VtB = bp + BVT;
#pragma unroll
    for (int i = 0; i < 2; i++)
#pragma unroll
        for (int j = 0; j < 2; j++) {
            int gn = n0 + wn + j * 16 + lr;
            int gmb = m0 + wm + i * 16 + lq * 4;
            float b = in_b[gn];
            if (gn < 2 * DD) {
#pragma unroll
                for (int r4 = 0; r4 < 4; r4++)
                    QKB[(size_t)(gmb + r4) * 1024 + gn] = __float2bfloat16(acc[i][j][r4] + b);
            } else {
                union { uint2 u; unsigned short us[4]; } o;
#pragma unroll
                for (int r4 = 0; r4 < 4; r4++) {
                    bf16 t2 = __float2bfloat16(acc[i][j][r4] + b);
                    o.us[r4] = *(unsigned short*)&t2;
                }
                *(uint2*)&VtB[(size_t)(gn - 2 * DD) * NT + gmb] = o.u;
            }
        }
}

// ---------------- E-GEMM: E = exp(scale * A@B^T), bf16 in/out, 128x128 ----------------
// STATS=1: also write per-tile row expsums. blockIdx.z==4 (STATS=0 launch): abc fold.
template <int STATS>
__global__ __launch_bounds__(256) void k_score(
    const bf16* __restrict__ Ab, int lda, int aZ,
    const bf16* __restrict__ Bb, int ldb, int bZ,
    bf16* __restrict__ E, float* ws)
{
    int tid = threadIdx.x;
    if (!STATS && blockIdx.z == 4) {
        bf16* bp = (bf16*)(ws + BF_BASE);
        int flat = blockIdx.y * 12 + blockIdx.x;
        int w = tid >> 6, lane = tid & 63;
        for (int t = w; t < 43; t += 4) {
            int row = flat * 43 + t;
            if (row >= NH * NT) break;
            int hh = row / NT, n = row % NT;
            const unsigned short* k2 = (const unsigned short*)(bp + BK2 + (size_t)n * 512 + hh * DHD);
            const float* av = ws + OFF_AV + hh * DHD;
            const float* bv = ws + OFF_BV + hh * DHD;
            int d = lane * 2;
            float k0 = __uint_as_float((unsigned)k2[d] << 16);
            float k1 = __uint_as_float((unsigned)k2[d + 1] << 16);
            float a = av[d] * k0 + av[d + 1] * k1;
            float b = bv[d] * k0 + bv[d + 1] * k1;
            for (int off = 32; off; off >>= 1) { a += __shfl_xor(a, off); b += __shfl_xor(b, off); }
            if (lane == 0) { ws[OFF_AARR + row] = a * RSQRT_DH; ws[OFF_BARR + row] = b * RSQRT_DH; }
        }
        return;
    }
    int z = blockIdx.z;
    const __bf16* A = (const __bf16*)Ab + (size_t)z * aZ;
    const __bf16* B = (const __bf16*)Bb + (size_t)z * bZ;
    int m0 = blockIdx.y * 128, n0 = blockIdx.x * 128;
    __shared__ __bf16 As[128 * 40];
    __shared__ __bf16 Bs[128 * 40];
    __shared__ float sSum[4][64];
    int r = tid >> 1, hh = tid & 1;
    int w = tid >> 6, lane = tid & 63;
    int wm = (w & 1) * 64, wn = (w >> 1) * 64;
    int lr = lane & 15, lq = lane >> 4;
    f32x4 acc[4][4];
#pragma unroll
    for (int i = 0; i < 4; i++)
#pragma unroll
        for (int j = 0; j < 4; j++) acc[i][j] = (f32x4){0.f, 0.f, 0.f, 0.f};

    const __bf16* arow = A + (size_t)(m0 + r) * lda + hh * 16;
    const __bf16* brow = B + (size_t)(n0 + r) * ldb + hh * 16;
    __bf16* awr = &As[r * 40 + hh * 16];
    __bf16* bwr = &Bs[r * 40 + hh * 16];

    for (int k0 = 0; k0 < DHD; k0 += 32) {
        uint4 a0 = *(const uint4*)(arow + k0);
        uint4 a1 = *(const uint4*)(arow + k0 + 8);
        uint4 b0 = *(const uint4*)(brow + k0);
        uint4 b1 = *(const uint4*)(brow + k0 + 8);
        __syncthreads();
        *(uint4*)awr = a0; *(uint4*)(awr + 8) = a1;
        *(uint4*)bwr = b0; *(uint4*)(bwr + 8) = b1;
        __syncthreads();
        bf16x8 af[4], bfr[4];
#pragma unroll
        for (int i = 0; i < 4; i++) af[i] = *(bf16x8*)&As[(wm + i * 16 + lr) * 40 + lq * 8];
#pragma unroll
        for (int j = 0; j < 4; j++) bfr[j] = *(bf16x8*)&Bs[(wn + j * 16 + lr) * 40 + lq * 8];
#pragma unroll
        for (int i = 0; i < 4; i++)
#pragma unroll
            for (int j = 0; j < 4; j++)
                acc[i][j] = __builtin_amdgcn_mfma_f32_16x16x32_bf16(af[i], bfr[j], acc[i][j], 0, 0, 0);
    }
    bf16* Ez = E + (size_t)z * NT * NT;
#pragma unroll
    for (int i = 0; i < 4; i++)
#pragma unroll
        for (int r4 = 0; r4 < 4; r4++) {
            int gm = m0 + wm + i * 16 + lq * 4 + r4;
            float s = 0.f;
#pragma unroll
            for (int j = 0; j < 4; j++) {
                float e = __expf(acc[i][j][r4] * RSQRT_DH);
                Ez[(size_t)gm * NT + n0 + wn + j * 16 + lr] = __float2bfloat16(e);
                s += e;
            }
            if (STATS) {
                for (int off = 1; off < 16; off <<= 1) s += __shfl_xor(s, off);
                if (lr == 0) sSum[w][i * 16 + lq * 4 + r4] = s;
            }
        }
    if (STATS) {
        __syncthreads();
        if (tid < 128) {
            int lidx = tid & 63, wb = tid >> 6;
            ws[OFF_STAT + ((size_t)z * NT + m0 + tid) * 12 + blockIdx.x] = sSum[wb][lidx] + sSum[wb + 2][lidx];
        }
    }
}

// P@V: 64m x 128n tiles, split-K=2 disjoint partials, E staged by copy, den from stats
__global__ __launch_bounds__(256) void k_pv(const bf16* __restrict__ E, float* ws) {
    bf16* bp = (bf16*)(ws + BF_BASE);
    int h = blockIdx.z;
    int m0 = blockIdx.y * 64;
    int ks = blockIdx.x;
    const int KCH = NT / 2;
    int kbeg = ks * KCH;
    __shared__ __bf16 As[64 * 40];
    __shared__ __bf16 Bs[128 * 40];
    __shared__ float sI[64];
    int tid = threadIdx.x;
    if (tid < 64) {
        const float* st = ws + OFF_STAT + (size_t)(h * NT + m0 + tid) * 12;
        float den = 0.f;
#pragma unroll
        for (int t2 = 0; t2 < 12; t2++) den += st[t2];
        sI[tid] = 1.f / den;
    }
    int rA = tid >> 2, quadA = tid & 3;
    int rB = tid >> 1, hhB = tid & 1;
    int w = tid >> 6, lane = tid & 63;
    int wm = (w & 1) * 32, wn = (w >> 1) * 64;
    int lr = lane & 15, lq = lane >> 4;
    const __bf16* Eh = (const __bf16*)E + (size_t)h * NT * NT;
    const __bf16* arow = Eh + (size_t)(m0 + rA) * NT + quadA * 8;
    const __bf16* brow = (const __bf16*)(bp + BVT) + ((size_t)h * 128 + rB) * NT + hhB * 16;
    __bf16* awr = &As[rA * 40 + quadA * 8];
    __bf16* bwr = &Bs[rB * 40 + hhB * 16];
    f32x4 acc[2][4];
#pragma unroll
    for (int i = 0; i < 2; i++)
#pragma unroll
        for (int j = 0; j < 4; j++) acc[i][j] = (f32x4){0.f, 0.f, 0.f, 0.f};

    for (int k0 = kbeg; k0 < kbeg + KCH; k0 += 32) {
        uint4 av = *(const uint4*)(arow + k0);
        uint4 b0 = *(const uint4*)(brow + k0);
        uint4 b1 = *(const uint4*)(brow + k0 + 8);
        __syncthreads();
        *(uint4*)awr = av;
        *(uint4*)bwr = b0; *(uint4*)(bwr + 8) = b1;
        __syncthreads();
        bf16x8 af[2], bfr[4];
#pragma unroll
        for (int i = 0; i < 2; i++) af[i] = *(bf16x8*)&As[(wm + i * 16 + lr) * 40 + lq * 8];
#pragma unroll
        for (int j = 0; j < 4; j++) bfr[j] = *(bf16x8*)&Bs[(wn + j * 16 + lr) * 40 + lq * 8];
#pragma unroll
        for (int i = 0; i < 2; i++)
#pragma unroll
            for (int j = 0; j < 4; j++)
                acc[i][j] = __builtin_amdgcn_mfma_f32_16x16x32_bf16(af[i], bfr[j], acc[i][j], 0, 0, 0);
    }
    float* dst = ws + (ks == 0 ? OFF_CTX : OFF_CTX1);
#pragma unroll
    for (int i = 0; i < 2; i++)
#pragma unroll
        for (int r4 = 0; r4 < 4; r4++) {
            int lrow = wm + i * 16 + lq * 4 + r4;
            float ri = sI[lrow];
#pragma unroll
            for (int j = 0; j < 4; j++) {
                int gn = wn + j * 16 + lr;
                dst[(size_t)(m0 + lrow) * DD + h * DHD + gn] = acc[i][j][r4] * ri;
            }
        }
}

// attn_out = (ctx0+ctx1) @ out_w^T + out_b -> att fp32 + attB bf16, + fused pooling
__global__ __launch_bounds__(256) void k_oproj(const float* __restrict__ out_b, float* ws) {
    bf16* bp = (bf16*)(ws + BF_BASE);
    int m0 = blockIdx.y * 64, n0 = blockIdx.x * 64;
    __shared__ __bf16 As[64 * 40];
    __shared__ __bf16 Bs[64 * 40];
    __shared__ float ps[64];
    int tid = threadIdx.x;
    int r = tid >> 2, quad = tid & 3;
    int w = tid >> 6, lane = tid & 63;
    int wm = (w & 1) * 32, wn = (w >> 1) * 32;
    int lr = lane & 15, lq = lane >> 4;
    f32x4 acc[2][2];
#pragma unroll
    for (int i = 0; i < 2; i++)
#pragma unroll
        for (int j = 0; j < 2; j++) acc[i][j] = (f32x4){0.f, 0.f, 0.f, 0.f};
    if (tid < 64) ps[tid] = 0.f;

    const float* a0 = ws + OFF_CTX  + (size_t)(m0 + r) * DD + quad * 8;
    const float* a1 = ws + OFF_CTX1 + (size_t)(m0 + r) * DD + quad * 8;
    const __bf16* brow = (const __bf16*)(bp + BOUTW) + (size_t)(n0 + r) * 512 + quad * 8;
    __bf16* awr = &As[r * 40 + quad * 8];
    __bf16* bwr = &Bs[r * 40 + quad * 8];

    for (int k0 = 0; k0 < DD; k0 += 32) {
        __bf16 ta[8] __attribute__((aligned(16)));
#pragma unroll
        for (int q = 0; q < 4; q++) {
            float2 x = *(const float2*)(a0 + k0 + 2 * q);
            float2 y = *(const float2*)(a1 + k0 + 2 * q);
            ta[2 * q]     = (__bf16)(x.x + y.x);
            ta[2 * q + 1] = (__bf16)(x.y + y.y);
        }
        uint4 bbv = *(const uint4*)(brow + k0);
        __syncthreads();
        *(bf16x8*)awr = *(bf16x8*)ta;
        *(uint4*)bwr = bbv;
        __syncthreads();
        bf16x8 af[2], bfr[2];
#pragma unroll
        for (int i = 0; i < 2; i++) af[i] = *(bf16x8*)&As[(wm + i * 16 + lr) * 40 + lq * 8];
#pragma unroll
        for (int j = 0; j < 2; j++) bfr[j] = *(bf16x8*)&Bs[(wn + j * 16 + lr) * 40 + lq * 8];
#pragma unroll
        for (int i = 0; i < 2; i++)
#pragma unroll
            for (int j = 0; j < 2; j++)
                acc[i][j] = __builtin_amdgcn_mfma_f32_16x16x32_bf16(af[i], bfr[j], acc[i][j], 0, 0, 0);
    }
    float* att = ws + OFF_ATT;
    bf16* attB = bp + BATT;
#pragma unroll
    for (int j = 0; j < 2; j++) {
        int gn = n0 + wn + j * 16 + lr;
        float b = out_b[gn];
        float colsum = 0.f;
#pragma unroll
        for (int i = 0; i < 2; i++)
#pragma unroll
            for (int r4 = 0; r4 < 4; r4++) {
                int gm = m0 + wm + i * 16 + lq * 4 + r4;
                float v = acc[i][j][r4] + b;
                att[(size_t)gm * DD + gn] = v;
                attB[(size_t)gm * 512 + gn] = __float2bfloat16(v);
                colsum += v;
            }
        atomicAdd(&ps[wn + j * 16 + lr], colsum);
    }
    __syncthreads();
    if (tid < 64) atomicAdd(&ws[OFF_POOL + n0 + tid], ps[tid]);
}

// triple GEMM A=attB: K2B (0-7) | Q0B (8-15) | H0 fp32 (16-21) + head block (22)
__global__ __launch_bounds__(256) void k_trip(
    const float* __restrict__ in_b, const float* __restrict__ ref_b1,
    const float* __restrict__ icw1, const float* __restrict__ icb1,
    const float* __restrict__ icw2, const float* __restrict__ icb2,
    float* ws, float* out)
{
    bf16* bp = (bf16*)(ws + BF_BASE);
    __shared__ __bf16 As[64 * 40];
    __shared__ __bf16 Bs[64 * 40];
    __shared__ float h1[128];
    __shared__ float lg[MAXI];
    int bx = blockIdx.x, tid = threadIdx.x;
    if (bx == 22) {
        if (blockIdx.y != 0) return;
        int w = tid >> 6, lane = tid & 63;
        const float* pp = ws + OFF_POOL + lane * 8;
        float4 p0 = *(const float4*)pp, p1 = *(const float4*)(pp + 4);
        float p8[8] = {p0.x, p0.y, p0.z, p0.w, p1.x, p1.y, p1.z, p1.w};
        for (int t = 0; t < 32; t++) {
            int row = w * 32 + t;
            const float* wr = icw1 + (size_t)row * DD + lane * 8;
            float4 a = *(const float4*)wr, b = *(const float4*)(wr + 4);
            float d = a.x * p8[0] + a.y * p8[1] + a.z * p8[2] + a.w * p8[3]
                    + b.x * p8[4] + b.y * p8[5] + b.z * p8[6] + b.w * p8[7];
            for (int off = 32; off; off >>= 1) d += __shfl_xor(d, off);
            if (lane == 0) h1[row] = fmaxf(d * (1.0f / NT) + icb1[row], 0.f);
        }
        __syncthreads();
        if (tid < MAXI) {
            float s = icb2[tid];
            for (int j = 0; j < 128; j++) s += icw2[tid * 128 + j] * h1[j];
            lg[tid] = s;
        }
        __syncthreads();
        if (tid == 0) {
            int best = 0; float bv = lg[0];
            for (int m = 1; m < MAXI; m++) if (lg[m] > bv) { bv = lg[m]; best = m; }
            int ni = best + 1;
            for (int i = 0; i < MAXI; i++) out[10 + i] = (i < ni) ? 1.f : 0.f;
        }
        return;
    }
    const __bf16* B; const float* bias; int n0, mode;
    bf16* Cb = nullptr; float* Cf = nullptr;
    if (bx < 8)       { B = (const __bf16*)(bp + BINW) + (size_t)512 * 512; bias = in_b + DD;   Cb = bp + BK2; n0 = bx * 64; mode = 0; }
    else if (bx < 16) { B = (const __bf16*)(bp + BM2);                      bias = ws + OFF_B2; Cb = bp + BQ0; n0 = (bx - 8) * 64; mode = 0; }
    else              { B = (const __bf16*)(bp + BRW1);                     bias = ref_b1;      Cf = ws + OFF_H0; n0 = (bx - 16) * 64; mode = 1; }
    int m0 = blockIdx.y * 64;
    int r = tid >> 2, quad = tid & 3;
    int w = tid >> 6, lane = tid & 63;
    int wm = (w & 1) * 32, wn = (w >> 1) * 32;
    int lr = lane & 15, lq = lane >> 4;
    f32x4 acc[2][2];
#pragma unroll
    for (int i = 0; i < 2; i++)
#pragma unroll
        for (int j = 0; j < 2; j++) acc[i][j] = (f32x4){0.f, 0.f, 0.f, 0.f};

    const __bf16* arow = (const __bf16*)(bp + BATT) + (size_t)(m0 + r) * 512 + quad * 8;
    const __bf16* brow = B + (size_t)(n0 + r) * 512 + quad * 8;
    __bf16* awr = &As[r * 40 + quad * 8];
    __bf16* bwr = &Bs[r * 40 + quad * 8];

    for (int k0 = 0; k0 < DD; k0 += 32) {
        uint4 av = *(const uint4*)(arow + k0);
        uint4 bv = *(const uint4*)(brow + k0);
        __syncthreads();
        *(uint4*)awr = av;
        *(uint4*)bwr = bv;
        __syncthreads();
        bf16x8 af[2], bfr[2];
#pragma unroll
        for (int i = 0; i < 2; i++) af[i] = *(bf16x8*)&As[(wm + i * 16 + lr) * 40 + lq * 8];
#pragma unroll
        for (int j = 0; j < 2; j++) bfr[j] = *(bf16x8*)&Bs[(wn + j * 16 + lr) * 40 + lq * 8];
#pragma unroll
        for (int i = 0; i < 2; i++)
#pragma unroll
            for (int j = 0; j < 2; j++)
                acc[i][j] = __builtin_amdgcn_mfma_f32_16x16x32_bf16(af[i], bfr[j], acc[i][j], 0, 0, 0);
    }
#pragma unroll
    for (int i = 0; i < 2; i++)
#pragma unroll
        for (int r4 = 0; r4 < 4; r4++) {
            int gm = m0 + wm + i * 16 + lq * 4 + r4;
#pragma unroll
            for (int j = 0; j < 2; j++) {
                int gn = n0 + wn + j * 16 + lr;
                float v = acc[i][j][r4] + bias[gn];
                if (mode == 0) Cb[(size_t)gm * 512 + gn] = __float2bfloat16(v);
                else           Cf[(size_t)gm * 384 + gn] = v;
            }
        }
}

// fused: logits = relu(H0+delta)@rw2B^T + b2 in LDS, then softdot -> so/eo
__global__ __launch_bounds__(256) void k_lgs(
    const float* __restrict__ rw1, const float* __restrict__ rb2,
    const float* __restrict__ wp, int l, float* ws)
{
    bf16* bp = (bf16*)(ws + BF_BASE);
    __shared__ float dsh[128];
    __shared__ __bf16 As[64 * 136];
    __shared__ __bf16 Bs[64 * 136];
    __shared__ __bf16 Ls[64 * 208];
    int tid = threadIdx.x;
    int m0 = blockIdx.x * 64;
    int i_int = m0 / NT;
    int nbase = m0 % NT;
    if (blockIdx.x == 0 && tid < 11) ws[OFF_SCAL + SC_DSDE + tid] = 0.f;   // dsde[10] + ticket
    if (tid < 128) {
        float s_i = ws[OFF_SCAL + SC_START + i_int], e_i = ws[OFF_SCAL + SC_END + i_int];
        const float* wr = rw1 + (size_t)(l * 128 + tid) * 514;
        dsh[tid] = s_i * wr[512] + e_i * wr[513];
    }
    __syncthreads();
    int r = tid >> 2, quad = tid & 3;
    {
        const float* arow = ws + OFF_H0 + (size_t)(nbase + r) * 384 + l * 128 + quad * 32;
        __bf16 tmp[32] __attribute__((aligned(16)));
#pragma unroll
        for (int q = 0; q < 16; q++) {
            float2 f = *(const float2*)(arow + 2 * q);
            int jj = quad * 32 + 2 * q;
            tmp[2 * q]     = (__bf16)fmaxf(f.x + dsh[jj], 0.f);
            tmp[2 * q + 1] = (__bf16)fmaxf(f.y + dsh[jj + 1], 0.f);
        }
        __bf16* aw = &As[r * 136 + quad * 32];
#pragma unroll
        for (int q = 0; q < 4; q++) *(bf16x8*)(aw + q * 8) = *(bf16x8*)(tmp + q * 8);
    }
    int w = tid >> 6, lane = tid & 63;
    int wm = (w & 1) * 32, wn = (w >> 1) * 32;
    int lr = lane & 15, lq = lane >> 4;
    const __bf16* rw2b = (const __bf16*)(bp + BRW2) + (size_t)l * 200 * 128;
    for (int nt = 0; nt < 4; nt++) {
        int n0 = nt * 64;
        int gnr = n0 + r;
        uint4 b0 = {0, 0, 0, 0}, b1 = {0, 0, 0, 0}, b2v = {0, 0, 0, 0}, b3 = {0, 0, 0, 0};
        if (gnr < 200) {
            const __bf16* brow = rw2b + (size_t)gnr * 128 + quad * 32;
            b0 = *(const uint4*)brow; b1 = *(const uint4*)(brow + 8);
            b2v = *(const uint4*)(brow + 16); b3 = *(const uint4*)(brow + 24);
        }
        __syncthreads();
        {
            __bf16* bw = &Bs[r * 136 + quad * 32];
            *(uint4*)bw = b0; *(uint4*)(bw + 8) = b1;
            *(uint4*)(bw + 16) = b2v; *(uint4*)(bw + 24) = b3;
        }
        __syncthreads();
        f32x4 acc[2][2];
#pragma unroll
        for (int i = 0; i < 2; i++)
#pragma unroll
            for (int j = 0; j < 2; j++) acc[i][j] = (f32x4){0.f, 0.f, 0.f, 0.f};
#pragma unroll
        for (int kk = 0; kk < 4; kk++) {
            bf16x8 af[2], bfr[2];
#pragma unroll
            for (int i = 0; i < 2; i++) af[i] = *(bf16x8*)&As[(wm + i * 16 + lr) * 136 + kk * 32 + lq * 8];
#pragma unroll
            for (int j = 0; j < 2; j++) bfr[j] = *(bf16x8*)&Bs[(wn + j * 16 + lr) * 136 + kk * 32 + lq * 8];
#pragma unroll
            for (int i = 0; i < 2; i++)
#pragma unroll
                for (int j = 0; j < 2; j++)
                    acc[i][j] = __builtin_amdgcn_mfma_f32_16x16x32_bf16(af[i], bfr[j], acc[i][j], 0, 0, 0);
        }
#pragma unroll
        for (int i = 0; i < 2; i++)
#pragma unroll
            for (int r4 = 0; r4 < 4; r4++) {
                int rl = wm + i * 16 + lq * 4 + r4;
#pragma unroll
                for (int j = 0; j < 2; j++) {
                    int gn = n0 + wn + j * 16 + lr;
                    if (gn < 200) Ls[rl * 208 + gn] = (__bf16)(acc[i][j][r4] + rb2[gn]);
                }
            }
    }
    __syncthreads();
    {
        int rloc = tid >> 2, q = tid & 3;
        int c0 = q * 50;
        const unsigned short* lrow = (const unsigned short*)&Ls[rloc * 208];
        float m = -1e30f;
#pragma unroll
        for (int c = 0; c < 50; c++)
            m = fmaxf(m, __uint_as_float((unsigned)lrow[c0 + c] << 16));
        m = fmaxf(m, __shfl_xor(m, 1));
        float den = 0.f, num = 0.f;
#pragma unroll
        for (int c = 0; c < 50; c++) {
            float p = __expf(__uint_as_float((unsigned)lrow[c0 + c] << 16) - m);
            den += p;
            int wc = c0 + c; if (wc >= NBINS) wc -= NBINS;
            num += p * wp[wc];
        }
        den += __shfl_xor(den, 1);
        num += __shfl_xor(num, 1);
        int n = nbase + rloc;
        if (q == 0)      ws[OFF_SOFF + (size_t)i_int * NT + n] = num / den;
        else if (q == 2) ws[OFF_EOFF + (size_t)i_int * NT + n] = num / den;
    }
}

// full-K: P = E0 @ U^T (U on-the-fly), in-block ratios + dsde atomics + ticket update
// grid (24, 4)
__global__ __launch_bounds__(256) void k_egf(const bf16* __restrict__ E0, float* ws, float* out, int l) {
    int h = blockIdx.y;
    int m0 = blockIdx.x * 64;
    __shared__ __bf16 As[64 * 72];
    __shared__ __bf16 Bs[16 * 72];
    __shared__ float Ps[64 * 17];
    int tid = threadIdx.x;
    int w = tid >> 6, lane = tid & 63;
    int lr = lane & 15, lq = lane >> 4;
    int wm = w * 16;
    int r = tid >> 2, quad = tid & 3;   // A: 64 rows x 16 elems each
    const unsigned short* arow =
        (const unsigned short*)((const __bf16*)E0 + (size_t)h * NT * NT + (size_t)(m0 + r) * NT) + quad * 16;
    f32x4 acc = (f32x4){0.f, 0.f, 0.f, 0.f};
    int bc = tid >> 4, bk = tid & 15;   // 16 cols (15 used) x 16 k-groups of 4
    int bvalid = (bc < 15);
    int ii = bc / 3, tt = bc - ii * 3;
    if (ii > 4) ii = 4;
    float s_i = ws[OFF_SCAL + SC_START + ii], e_i = ws[OFF_SCAL + SC_END + ii];
    const float* Ar = ws + OFF_AARR + h * NT;
    const float* Br = ws + OFF_BARR + h * NT;
    const float* fo = ws + (tt == 2 ? OFF_EOFF : OFF_SOFF) + (size_t)ii * NT;

    for (int k0 = 0; k0 < NT; k0 += 64) {
        uint4 a0 = *(const uint4*)(arow + k0);
        uint4 a1 = *(const uint4*)(arow + k0 + 8);
        float bv[4] = {0.f, 0.f, 0.f, 0.f};
        if (bvalid) {
            float4 a4 = *(const float4*)(Ar + k0 + bk * 4);
            float4 b4 = *(const float4*)(Br + k0 + bk * 4);
            bv[0] = __expf(s_i * a4.x + e_i * b4.x);
            bv[1] = __expf(s_i * a4.y + e_i * b4.y);
            bv[2] = __expf(s_i * a4.z + e_i * b4.z);
            bv[3] = __expf(s_i * a4.w + e_i * b4.w);
            if (tt) {
                float4 f4 = *(const float4*)(fo + k0 + bk * 4);
                bv[0] *= f4.x; bv[1] *= f4.y; bv[2] *= f4.z; bv[3] *= f4.w;
            }
        }
        __syncthreads();
        *(uint4*)&As[r * 72 + quad * 16] = a0;
        *(uint4*)&As[r * 72 + quad * 16 + 8] = a1;
        if (bvalid) {
            __bf16* bw = &Bs[bc * 72 + bk * 4];
            bw[0] = (__bf16)bv[0]; bw[1] = (__bf16)bv[1]; bw[2] = (__bf16)bv[2]; bw[3] = (__bf16)bv[3];
        }
        __syncthreads();
#pragma unroll
        for (int ks = 0; ks < 2; ks++) {
            bf16x8 af = *(bf16x8*)&As[(wm + lr) * 72 + ks * 32 + lq * 8];
            bf16x8 bf0 = *(bf16x8*)&Bs[lr * 72 + ks * 32 + lq * 8];
            acc = __builtin_amdgcn_mfma_f32_16x16x32_bf16(af, bf0, acc, 0, 0, 0);
        }
    }
#pragma unroll
    for (int reg = 0; reg < 4; reg++)
        Ps[(wm + lq * 4 + reg) * 17 + lr] = acc[reg];
    __syncthreads();
    if (w == 0) {   // wave 0: lane = row
        const float* P = &Ps[lane * 17];
        float loc[10];
#pragma unroll
        for (int i = 0; i < MAXI; i++) {
            float dn = P[i * 3];
            loc[i]        = P[i * 3 + 1] / dn;
            loc[MAXI + i] = P[i * 3 + 2] / dn;
        }
#pragma unroll
        for (int c = 0; c < 10; c++)
            for (int off = 32; off; off >>= 1) loc[c] += __shfl_xor(loc[c], off);
        if (lane == 0) {
#pragma unroll
            for (int c = 0; c < 10; c++) atomicAdd(&ws[OFF_SCAL + SC_DSDE + c], loc[c]);
            __threadfence();
            unsigned old = atomicAdd((unsigned*)&ws[OFF_SCAL + SC_CNT], 1u);
            if (old == 95) {   // last of 96 blocks
                for (int i = 0; i < MAXI; i++) {
                    float ds = atomicAdd(&ws[OFF_SCAL + SC_DSDE + i], 0.f);
                    float de = atomicAdd(&ws[OFF_SCAL + SC_DSDE + MAXI + i], 0.f);
                    float ns = ws[OFF_SCAL + SC_START + i] + ds * 0.25f;   // 1/H
                    float ne = ws[OFF_SCAL + SC_END + i]   + de * 0.25f;
                    ws[OFF_SCAL + SC_START + i] = ns;
                    ws[OFF_SCAL + SC_END + i]   = ne;
                    if (l == NL - 1) { out[2 * i] = ns; out[2 * i + 1] = ne; }
                }
            }
        }
    }
}

// -------------------------------------------------------------------------
extern "C" void kernel_launch(void* const* d_in, const int* in_sizes, int n_in,
                              void* d_out, int out_size, void* d_ws, size_t ws_size,
                              hipStream_t stream) {
    const float* emb    = (const float*)d_in[0];
    const float* tpos   = (const float*)d_in[1];
    const float* W_time = (const float*)d_in[3];
    const float* b_time = (const float*)d_in[4];
    const float* in_w   = (const float*)d_in[5];
    const float* in_b   = (const float*)d_in[6];
    const float* out_w  = (const float*)d_in[7];
    const float* out_b  = (const float*)d_in[8];
    const float* ic_w1  = (const float*)d_in[9];
    const float* ic_b1  = (const float*)d_in[10];
    const float* ic_w2  = (const float*)d_in[11];
    const float* ic_b2  = (const float*)d_in[12];
    const float* ref_w1 = (const float*)d_in[13];
    const float* ref_b1 = (const float*)d_in[14];
    const float* ref_w2 = (const float*)d_in[15];
    const float* ref_b2 = (const float*)d_in[16];
    const float* wp     = (const float*)d_in[17];
    const float* qp_w   = (const float*)d_in[18];
    const float* qp_b   = (const float*)d_in[19];
    float* ws  = (float*)d_ws;
    float* out = (float*)d_out;
    bf16* E = (bf16*)(ws + OFF_E);
    bf16* bp = (bf16*)(ws + BF_BASE);

    // prologue: M2B | uv | pre | weight-to-bf16 converts
    k_misc<<<98, 256, 0, stream>>>(tpos, in_w, in_b, out_w, ref_w1, ref_w2, qp_w, qp_b, ws);

    // qkv (+x fusion) -> QKB bf16, VtB bf16
    k_qkv<<<dim3(24, 24), 256, 0, stream>>>(emb, tpos, W_time, b_time, in_b, ws);
    // E1 = exp(QK^T/sqrt(dh)) + per-tile expsums
    k_score<1><<<dim3(12, 12, NH), 256, 0, stream>>>(
        bp + BQKB, 1024, DHD, bp + BQKB + 512, 1024, DHD, E, ws);
    k_pv<<<dim3(2, NT / 64, NH), 256, 0, stream>>>(E, ws);
    k_oproj<<<dim3(8, 24), 256, 0, stream>>>(out_b, ws);

    // K2B | Q0B | H0 | head
    k_trip<<<dim3(23, 24), 256, 0, stream>>>(in_b, ref_b1, ic_w1, ic_b1, ic_w2, ic_b2, ws, out);

    // E0 = exp(Q0 K2^T / sqrt(dh)) + abc fold (z==4)
    k_score<0><<<dim3(12, 12, 5), 256, 0, stream>>>(
        bp + BQ0, 512, DHD, bp + BK2, 512, DHD, E, ws);

    for (int l = 0; l < NL; l++) {
        k_lgs<<<120, 256, 0, stream>>>(ref_w1, ref_b2 + l * 200, wp, l, ws);
        k_egf<<<dim3(24, NH), 256, 0, stream>>>(E, ws, out, l);
    }
}

// Round 11
// 304.768 us; speedup vs baseline: 1.2395x; 1.1577x over previous
//
#include <hip/hip_runtime.h>
#include <hip/hip_bf16.h>

typedef __hip_bfloat16 bf16;
typedef __bf16 bf16x8 __attribute__((ext_vector_type(8)));
typedef float f32x4 __attribute__((ext_vector_type(4)));

#define DD   512
#define NT   1536
#define NH   4
#define DHD  128
#define NBINS 100
#define MAXI 5
#define NL   3
#define RSQRT_DH 0.08838834764831845f   // 1/sqrt(128)

// ---- fp32 workspace layout (float offsets) ----
#define OFF_ATT    ((size_t)0)                        // attn_out N x D (fp32, head)
#define OFF_CTX    (OFF_ATT  + (size_t)NT*DD)        // pv partial ks=0
#define OFF_CTX1   (OFF_CTX  + (size_t)NT*DD)        // pv partial ks=1
#define OFF_H0     (OFF_CTX1 + (size_t)NT*DD)        // N x 384 fp32
#define OFF_LG     (OFF_H0   + (size_t)NT*384)       // P slices [8][NH*NT][16]
#define OFF_AARR   (OFF_LG   + (size_t)8*NH*NT*16)
#define OFF_BARR   (OFF_AARR + (size_t)NH*NT)
#define OFF_AV     (OFF_BARR + (size_t)NH*NT)
#define OFF_BV     (OFF_AV   + (size_t)DD)
#define OFF_B2     (OFF_BV   + (size_t)DD)
#define OFF_SOFF   (OFF_B2   + (size_t)DD)
#define OFF_EOFF   (OFF_SOFF + (size_t)MAXI*NT)
#define OFF_STAT   (OFF_EOFF + (size_t)MAXI*NT)      // [NH*NT][12] expsums (MHA1)
#define OFF_POOL   (OFF_STAT + (size_t)NH*NT*12)
#define OFF_SCAL   (OFF_POOL + (size_t)DD)
#define OFF_E      (OFF_SCAL + (size_t)64)           // bf16 E region NH*NT*NT
#define SC_START 0
#define SC_END   5
#define SC_DSDE  10
#define SC_CNT   20
#define PSLICE   ((size_t)NH*NT*16)
// ---- bf16 pool (element offsets), starts after E ----
#define BF_BASE  (OFF_E + (size_t)NH*NT*NT/2)
#define BQKB   ((size_t)0)                   // [NT][1024] Q|K
#define BVT    (BQKB  + (size_t)NT*1024)     // [NH][128][NT]
#define BATT   (BVT   + (size_t)NH*128*NT)   // [NT][512]
#define BK2    (BATT  + (size_t)NT*512)
#define BQ0    (BK2   + (size_t)NT*512)
#define BM2    (BQ0   + (size_t)NT*512)      // [512][512]
#define BINW   (BM2   + (size_t)512*512)     // [1536][512]
#define BOUTW  (BINW  + (size_t)1536*512)    // [512][512]
#define BRW1   (BOUTW + (size_t)512*512)     // [384][512]
#define BRW2   (BRW1  + (size_t)384*512)     // [3][200][128]

__device__ __forceinline__ void cvt8(const float* s, bf16* d) {
    float4 f0 = *(const float4*)s, f1 = *(const float4*)(s + 4);
    union { uint4 u; unsigned short us[8]; } o;
    bf16 t;
    t = __float2bfloat16(f0.x); o.us[0] = *(unsigned short*)&t;
    t = __float2bfloat16(f0.y); o.us[1] = *(unsigned short*)&t;
    t = __float2bfloat16(f0.z); o.us[2] = *(unsigned short*)&t;
    t = __float2bfloat16(f0.w); o.us[3] = *(unsigned short*)&t;
    t = __float2bfloat16(f1.x); o.us[4] = *(unsigned short*)&t;
    t = __float2bfloat16(f1.y); o.us[5] = *(unsigned short*)&t;
    t = __float2bfloat16(f1.z); o.us[6] = *(unsigned short*)&t;
    t = __float2bfloat16(f1.w); o.us[7] = *(unsigned short*)&t;
    *(uint4*)d = o.u;
}

// -------------------------------------------------------------------------
// prologue: M2B GEMM (0-63) | uv (64-71) | pre (72) | weight converts (73-97)
__global__ __launch_bounds__(256) void k_misc(
    const float* __restrict__ tpos, const float* __restrict__ in_w,
    const float* __restrict__ in_b, const float* __restrict__ out_w,
    const float* __restrict__ ref_w1, const float* __restrict__ ref_w2,
    const float* __restrict__ qp_w, const float* __restrict__ qp_b, float* ws)
{
    __shared__ __bf16 As[64 * 40];
    __shared__ __bf16 Bs[64 * 40];
    __shared__ float smn[256], smx[256];
    bf16* bp = (bf16*)(ws + BF_BASE);
    int bx = blockIdx.x, tid = threadIdx.x;
    if (bx < 64) {
        int m0 = (bx >> 3) * 64, n0 = (bx & 7) * 64;
        int r = tid >> 2, quad = tid & 3;
        int w = tid >> 6, lane = tid & 63;
        int wm = (w & 1) * 32, wn = (w >> 1) * 32;
        int lr = lane & 15, lq = lane >> 4;
        f32x4 acc[2][2];
#pragma unroll
        for (int i = 0; i < 2; i++)
#pragma unroll
            for (int j = 0; j < 2; j++) acc[i][j] = (f32x4){0.f, 0.f, 0.f, 0.f};
        const float* arow = in_w + (size_t)(m0 + r) * DD + quad * 8;
        int kk = tid >> 3, g = tid & 7;
        for (int k0 = 0; k0 < DD; k0 += 32) {
            __bf16 ta[8] __attribute__((aligned(16)));
#pragma unroll
            for (int q = 0; q < 4; q++) {
                float2 f = *(const float2*)(arow + k0 + 2 * q);
                ta[2 * q] = (__bf16)f.x; ta[2 * q + 1] = (__bf16)f.y;
            }
            const float* bsrc = qp_w + (size_t)(k0 + kk) * 514 + n0 + g * 8;
            float4 b0 = *(const float4*)bsrc;
            float4 b1 = *(const float4*)(bsrc + 4);
            float bb[8] = {b0.x, b0.y, b0.z, b0.w, b1.x, b1.y, b1.z, b1.w};
            __syncthreads();
            *(bf16x8*)&As[r * 40 + quad * 8] = *(bf16x8*)ta;
#pragma unroll
            for (int q = 0; q < 8; q++) Bs[(g * 8 + q) * 40 + kk] = (__bf16)bb[q];
            __syncthreads();
            bf16x8 af[2], bfr[2];
#pragma unroll
            for (int i = 0; i < 2; i++) af[i] = *(bf16x8*)&As[(wm + i * 16 + lr) * 40 + lq * 8];
#pragma unroll
            for (int j = 0; j < 2; j++) bfr[j] = *(bf16x8*)&Bs[(wn + j * 16 + lr) * 40 + lq * 8];
#pragma unroll
            for (int i = 0; i < 2; i++)
#pragma unroll
                for (int j = 0; j < 2; j++)
                    acc[i][j] = __builtin_amdgcn_mfma_f32_16x16x32_bf16(af[i], bfr[j], acc[i][j], 0, 0, 0);
        }
        bf16* M2B = bp + BM2;
#pragma unroll
        for (int i = 0; i < 2; i++)
#pragma unroll
            for (int r4 = 0; r4 < 4; r4++) {
                int gm = m0 + wm + i * 16 + lq * 4 + r4;
#pragma unroll
                for (int j = 0; j < 2; j++)
                    M2B[(size_t)gm * 512 + n0 + wn + j * 16 + lr] = __float2bfloat16(acc[i][j][r4]);
            }
    } else if (bx < 72) {
        int w = tid >> 6, lane = tid & 63;
        float su8[8], sv8[8], sb8[8];
#pragma unroll
        for (int q = 0; q < 8; q++) {
            int c = lane * 8 + q;
            su8[q] = qp_w[(size_t)c * 514 + 512];
            sv8[q] = qp_w[(size_t)c * 514 + 513];
            sb8[q] = qp_b[c];
        }
        int base = (bx - 64) * 64 + w * 16;
        for (int t = 0; t < 16; t++) {
            int row = base + t;
            const float* wr = in_w + (size_t)row * DD + lane * 8;
            float4 x0 = *(const float4*)wr, x1 = *(const float4*)(wr + 4);
            float xa[8] = {x0.x, x0.y, x0.z, x0.w, x1.x, x1.y, x1.z, x1.w};
            float a = 0.f, b = 0.f, c2 = 0.f;
#pragma unroll
            for (int q = 0; q < 8; q++) { a += xa[q] * su8[q]; b += xa[q] * sv8[q]; c2 += xa[q] * sb8[q]; }
            for (int off = 32; off; off >>= 1) {
                a += __shfl_xor(a, off); b += __shfl_xor(b, off); c2 += __shfl_xor(c2, off);
            }
            if (lane == 0) {
                ws[OFF_AV + row] = a; ws[OFF_BV + row] = b; ws[OFF_B2 + row] = c2 + in_b[row];
            }
        }
    } else if (bx == 72) {
        ws[OFF_POOL + tid] = 0.f; ws[OFF_POOL + 256 + tid] = 0.f;
        float mn = 1e30f, mx = -1e30f;
        for (int i = tid; i < NT; i += 256) { float v = tpos[i]; mn = fminf(mn, v); mx = fmaxf(mx, v); }
        smn[tid] = mn; smx[tid] = mx; __syncthreads();
        for (int s = 128; s; s >>= 1) {
            if (tid < s) { smn[tid] = fminf(smn[tid], smn[tid + s]); smx[tid] = fmaxf(smx[tid], smx[tid + s]); }
            __syncthreads();
        }
        if (tid == 0) {
            float tmin = smn[0], tmax = smx[0];
            for (int i = 0; i < MAXI; i++) {
                ws[OFF_SCAL + SC_START + i] = tmin + (tmax - tmin) * (float)i / 5.0f;
                ws[OFF_SCAL + SC_END + i]   = tmin + (tmax - tmin) * (float)(i + 1) / 5.0f;
            }
        }
    } else if (bx < 89) {
        size_t start = (size_t)(bx - 73) * 6144;
        for (int it = 0; it < 24; it++) {
            size_t g = start + it * 256 + tid;
            cvt8(in_w + g * 8, bp + BINW + g * 8);
        }
    } else if (bx < 93) {
        size_t start = (size_t)(bx - 89) * 8192;
        for (int it = 0; it < 32; it++) {
            size_t g = start + it * 256 + tid;
            cvt8(out_w + g * 8, bp + BOUTW + g * 8);
        }
    } else if (bx < 97) {
        size_t start = (size_t)(bx - 93) * 6144;
        for (int it = 0; it < 24; it++) {
            size_t g = start + it * 256 + tid;
            int row = (int)(g >> 6), col = (int)(g & 63) * 8;
            const float* s = ref_w1 + (size_t)row * 514 + col;
            float buf[8];
#pragma unroll
            for (int q = 0; q < 4; q++) { float2 f = *(const float2*)(s + 2 * q); buf[2 * q] = f.x; buf[2 * q + 1] = f.y; }
            cvt8(buf, bp + BRW1 + (size_t)row * 512 + col);
        }
    } else {
        for (int it = 0; it < 38; it++) {
            size_t g = (size_t)it * 256 + tid;
            if (g < 9600) cvt8(ref_w2 + g * 8, bp + BRW2 + g * 8);
        }
    }
}

// qkv = (emb + t*wt + bt) @ in_w^T + in_b -> QKB bf16 (Q|K), VtB bf16 transposed
__global__ __launch_bounds__(256) void k_qkv(
    const float* __restrict__ emb, const float* __restrict__ t,
    const float* __restrict__ wt, const float* __restrict__ bt,
    const float* __restrict__ in_b, float* ws)
{
    bf16* bp = (bf16*)(ws + BF_BASE);
    int m0 = blockIdx.y * 64, n0 = blockIdx.x * 64;
    __shared__ __bf16 As[64 * 40];
    __shared__ __bf16 Bs[64 * 40];
    int tid = threadIdx.x;
    int r = tid >> 2, quad = tid & 3;
    int w = tid >> 6, lane = tid & 63;
    int wm = (w & 1) * 32, wn = (w >> 1) * 32;
    int lr = lane & 15, lq = lane >> 4;
    f32x4 acc[2][2];
#pragma unroll
    for (int i = 0; i < 2; i++)
#pragma unroll
        for (int j = 0; j < 2; j++) acc[i][j] = (f32x4){0.f, 0.f, 0.f, 0.f};

    float trow = t[m0 + r];
    const float* arow = emb + (size_t)(m0 + r) * DD + quad * 8;
    const __bf16* brow = (const __bf16*)(bp + BINW) + (size_t)(n0 + r) * 512 + quad * 8;
    __bf16* awr = &As[r * 40 + quad * 8];
    __bf16* bwr = &Bs[r * 40 + quad * 8];

    for (int k0 = 0; k0 < DD; k0 += 32) {
        __bf16 ta[8] __attribute__((aligned(16)));
#pragma unroll
        for (int q = 0; q < 4; q++) {
            float2 e = *(const float2*)(arow + k0 + 2 * q);
            float2 wv = *(const float2*)(wt + k0 + quad * 8 + 2 * q);
            float2 bv = *(const float2*)(bt + k0 + quad * 8 + 2 * q);
            ta[2 * q]     = (__bf16)(e.x + trow * wv.x + bv.x);
            ta[2 * q + 1] = (__bf16)(e.y + trow * wv.y + bv.y);
        }
        uint4 bbv = *(const uint4*)(brow + k0);
        __syncthreads();
        *(bf16x8*)awr = *(bf16x8*)ta;
        *(uint4*)bwr = bbv;
        __syncthreads();
        bf16x8 af[2], bfr[2];
#pragma unroll
        for (int i = 0; i < 2; i++) af[i] = *(bf16x8*)&As[(wm + i * 16 + lr) * 40 + lq * 8];
#pragma unroll
        for (int j = 0; j < 2; j++) bfr[j] = *(bf16x8*)&Bs[(wn + j * 16 + lr) * 40 + lq * 8];
#pragma unroll
        for (int i = 0; i < 2; i++)
#pragma unroll
            for (int j = 0; j < 2; j++)
                acc[i][j] = __builtin_amdgcn_mfma_f32_16x16x32_bf16(af[i], bfr[j], acc[i][j], 0, 0, 0);
    }
    bf16* QKB = bp + BQKB;
    bf16* VtB = bp + BVT;
#pragma unroll
    for (int i = 0; i < 2; i++)
#pragma unroll
        for (int j = 0; j < 2; j++) {
            int gn = n0 + wn + j * 16 + lr;
            int gmb = m0 + wm + i * 16 + lq * 4;
            float b = in_b[gn];
            if (gn < 2 * DD) {
#pragma unroll
                for (int r4 = 0; r4 < 4; r4++)
                    QKB[(size_t)(gmb + r4) * 1024 + gn] = __float2bfloat16(acc[i][j][r4] + b);
            } else {
                union { uint2 u; unsigned short us[4]; } o;
#pragma unroll
                for (int r4 = 0; r4 < 4; r4++) {
                    bf16 t2 = __float2bfloat16(acc[i][j][r4] + b);
                    o.us[r4] = *(unsigned short*)&t2;
                }
                *(uint2*)&VtB[(size_t)(gn - 2 * DD) * NT + gmb] = o.u;
            }
        }
}

// ---------------- E-GEMM: E = exp(scale * A@B^T), bf16 in/out, 128x128 ----------------
// STATS=1: also write per-tile row expsums. blockIdx.z==4 (STATS=0 launch): abc fold.
template <int STATS>
__global__ __launch_bounds__(256) void k_score(
    const bf16* __restrict__ Ab, int lda, int aZ,
    const bf16* __restrict__ Bb, int ldb, int bZ,
    bf16* __restrict__ E, float* ws)
{
    int tid = threadIdx.x;
    if (!STATS && blockIdx.z == 4) {
        bf16* bp = (bf16*)(ws + BF_BASE);
        int flat = blockIdx.y * 12 + blockIdx.x;
        int w = tid >> 6, lane = tid & 63;
        for (int t = w; t < 43; t += 4) {
            int row = flat * 43 + t;
            if (row >= NH * NT) break;
            int hh = row / NT, n = row % NT;
            const unsigned short* k2 = (const unsigned short*)(bp + BK2 + (size_t)n * 512 + hh * DHD);
            const float* av = ws + OFF_AV + hh * DHD;
            const float* bv = ws + OFF_BV + hh * DHD;
            int d = lane * 2;
            float k0 = __uint_as_float((unsigned)k2[d] << 16);
            float k1 = __uint_as_float((unsigned)k2[d + 1] << 16);
            float a = av[d] * k0 + av[d + 1] * k1;
            float b = bv[d] * k0 + bv[d + 1] * k1;
            for (int off = 32; off; off >>= 1) { a += __shfl_xor(a, off); b += __shfl_xor(b, off); }
            if (lane == 0) { ws[OFF_AARR + row] = a * RSQRT_DH; ws[OFF_BARR + row] = b * RSQRT_DH; }
        }
        return;
    }
    int z = blockIdx.z;
    const __bf16* A = (const __bf16*)Ab + (size_t)z * aZ;
    const __bf16* B = (const __bf16*)Bb + (size_t)z * bZ;
    int m0 = blockIdx.y * 128, n0 = blockIdx.x * 128;
    __shared__ __bf16 As[128 * 40];
    __shared__ __bf16 Bs[128 * 40];
    __shared__ float sSum[4][64];
    int r = tid >> 1, hh = tid & 1;
    int w = tid >> 6, lane = tid & 63;
    int wm = (w & 1) * 64, wn = (w >> 1) * 64;
    int lr = lane & 15, lq = lane >> 4;
    f32x4 acc[4][4];
#pragma unroll
    for (int i = 0; i < 4; i++)
#pragma unroll
        for (int j = 0; j < 4; j++) acc[i][j] = (f32x4){0.f, 0.f, 0.f, 0.f};

    const __bf16* arow = A + (size_t)(m0 + r) * lda + hh * 16;
    const __bf16* brow = B + (size_t)(n0 + r) * ldb + hh * 16;
    __bf16* awr = &As[r * 40 + hh * 16];
    __bf16* bwr = &Bs[r * 40 + hh * 16];

    for (int k0 = 0; k0 < DHD; k0 += 32) {
        uint4 a0 = *(const uint4*)(arow + k0);
        uint4 a1 = *(const uint4*)(arow + k0 + 8);
        uint4 b0 = *(const uint4*)(brow + k0);
        uint4 b1 = *(const uint4*)(brow + k0 + 8);
        __syncthreads();
        *(uint4*)awr = a0; *(uint4*)(awr + 8) = a1;
        *(uint4*)bwr = b0; *(uint4*)(bwr + 8) = b1;
        __syncthreads();
        bf16x8 af[4], bfr[4];
#pragma unroll
        for (int i = 0; i < 4; i++) af[i] = *(bf16x8*)&As[(wm + i * 16 + lr) * 40 + lq * 8];
#pragma unroll
        for (int j = 0; j < 4; j++) bfr[j] = *(bf16x8*)&Bs[(wn + j * 16 + lr) * 40 + lq * 8];
#pragma unroll
        for (int i = 0; i < 4; i++)
#pragma unroll
            for (int j = 0; j < 4; j++)
                acc[i][j] = __builtin_amdgcn_mfma_f32_16x16x32_bf16(af[i], bfr[j], acc[i][j], 0, 0, 0);
    }
    bf16* Ez = E + (size_t)z * NT * NT;
#pragma unroll
    for (int i = 0; i < 4; i++)
#pragma unroll
        for (int r4 = 0; r4 < 4; r4++) {
            int gm = m0 + wm + i * 16 + lq * 4 + r4;
            float s = 0.f;
#pragma unroll
            for (int j = 0; j < 4; j++) {
                float e = __expf(acc[i][j][r4] * RSQRT_DH);
                Ez[(size_t)gm * NT + n0 + wn + j * 16 + lr] = __float2bfloat16(e);
                s += e;
            }
            if (STATS) {
                for (int off = 1; off < 16; off <<= 1) s += __shfl_xor(s, off);
                if (lr == 0) sSum[w][i * 16 + lq * 4 + r4] = s;
            }
        }
    if (STATS) {
        __syncthreads();
        if (tid < 128) {
            int lidx = tid & 63, wb = tid >> 6;
            ws[OFF_STAT + ((size_t)z * NT + m0 + tid) * 12 + blockIdx.x] = sSum[wb][lidx] + sSum[wb + 2][lidx];
        }
    }
}

// P@V: 64m x 128n tiles, split-K=2 disjoint partials, E staged by copy, den from stats
__global__ __launch_bounds__(256) void k_pv(const bf16* __restrict__ E, float* ws) {
    bf16* bp = (bf16*)(ws + BF_BASE);
    int h = blockIdx.z;
    int m0 = blockIdx.y * 64;
    int ks = blockIdx.x;
    const int KCH = NT / 2;
    int kbeg = ks * KCH;
    __shared__ __bf16 As[64 * 40];
    __shared__ __bf16 Bs[128 * 40];
    __shared__ float sI[64];
    int tid = threadIdx.x;
    if (tid < 64) {
        const float* st = ws + OFF_STAT + (size_t)(h * NT + m0 + tid) * 12;
        float den = 0.f;
#pragma unroll
        for (int t2 = 0; t2 < 12; t2++) den += st[t2];
        sI[tid] = 1.f / den;
    }
    int rA = tid >> 2, quadA = tid & 3;
    int rB = tid >> 1, hhB = tid & 1;
    int w = tid >> 6, lane = tid & 63;
    int wm = (w & 1) * 32, wn = (w >> 1) * 64;
    int lr = lane & 15, lq = lane >> 4;
    const __bf16* Eh = (const __bf16*)E + (size_t)h * NT * NT;
    const __bf16* arow = Eh + (size_t)(m0 + rA) * NT + quadA * 8;
    const __bf16* brow = (const __bf16*)(bp + BVT) + ((size_t)h * 128 + rB) * NT + hhB * 16;
    __bf16* awr = &As[rA * 40 + quadA * 8];
    __bf16* bwr = &Bs[rB * 40 + hhB * 16];
    f32x4 acc[2][4];
#pragma unroll
    for (int i = 0; i < 2; i++)
#pragma unroll
        for (int j = 0; j < 4; j++) acc[i][j] = (f32x4){0.f, 0.f, 0.f, 0.f};

    for (int k0 = kbeg; k0 < kbeg + KCH; k0 += 32) {
        uint4 av = *(const uint4*)(arow + k0);
        uint4 b0 = *(const uint4*)(brow + k0);
        uint4 b1 = *(const uint4*)(brow + k0 + 8);
        __syncthreads();
        *(uint4*)awr = av;
        *(uint4*)bwr = b0; *(uint4*)(bwr + 8) = b1;
        __syncthreads();
        bf16x8 af[2], bfr[4];
#pragma unroll
        for (int i = 0; i < 2; i++) af[i] = *(bf16x8*)&As[(wm + i * 16 + lr) * 40 + lq * 8];
#pragma unroll
        for (int j = 0; j < 4; j++) bfr[j] = *(bf16x8*)&Bs[(wn + j * 16 + lr) * 40 + lq * 8];
#pragma unroll
        for (int i = 0; i < 2; i++)
#pragma unroll
            for (int j = 0; j < 4; j++)
                acc[i][j] = __builtin_amdgcn_mfma_f32_16x16x32_bf16(af[i], bfr[j], acc[i][j], 0, 0, 0);
    }
    float* dst = ws + (ks == 0 ? OFF_CTX : OFF_CTX1);
#pragma unroll
    for (int i = 0; i < 2; i++)
#pragma unroll
        for (int r4 = 0; r4 < 4; r4++) {
            int lrow = wm + i * 16 + lq * 4 + r4;
            float ri = sI[lrow];
#pragma unroll
            for (int j = 0; j < 4; j++) {
                int gn = wn + j * 16 + lr;
                dst[(size_t)(m0 + lrow) * DD + h * DHD + gn] = acc[i][j][r4] * ri;
            }
        }
}

// attn_out = (ctx0+ctx1) @ out_w^T + out_b -> att fp32 + attB bf16, + fused pooling
__global__ __launch_bounds__(256) void k_oproj(const float* __restrict__ out_b, float* ws) {
    bf16* bp = (bf16*)(ws + BF_BASE);
    int m0 = blockIdx.y * 64, n0 = blockIdx.x * 64;
    __shared__ __bf16 As[64 * 40];
    __shared__ __bf16 Bs[64 * 40];
    __shared__ float ps[64];
    int tid = threadIdx.x;
    int r = tid >> 2, quad = tid & 3;
    int w = tid >> 6, lane = tid & 63;
    int wm = (w & 1) * 32, wn = (w >> 1) * 32;
    int lr = lane & 15, lq = lane >> 4;
    f32x4 acc[2][2];
#pragma unroll
    for (int i = 0; i < 2; i++)
#pragma unroll
        for (int j = 0; j < 2; j++) acc[i][j] = (f32x4){0.f, 0.f, 0.f, 0.f};
    if (tid < 64) ps[tid] = 0.f;

    const float* a0 = ws + OFF_CTX  + (size_t)(m0 + r) * DD + quad * 8;
    const float* a1 = ws + OFF_CTX1 + (size_t)(m0 + r) * DD + quad * 8;
    const __bf16* brow = (const __bf16*)(bp + BOUTW) + (size_t)(n0 + r) * 512 + quad * 8;
    __bf16* awr = &As[r * 40 + quad * 8];
    __bf16* bwr = &Bs[r * 40 + quad * 8];

    for (int k0 = 0; k0 < DD; k0 += 32) {
        __bf16 ta[8] __attribute__((aligned(16)));
#pragma unroll
        for (int q = 0; q < 4; q++) {
            float2 x = *(const float2*)(a0 + k0 + 2 * q);
            float2 y = *(const float2*)(a1 + k0 + 2 * q);
            ta[2 * q]     = (__bf16)(x.x + y.x);
            ta[2 * q + 1] = (__bf16)(x.y + y.y);
        }
        uint4 bbv = *(const uint4*)(brow + k0);
        __syncthreads();
        *(bf16x8*)awr = *(bf16x8*)ta;
        *(uint4*)bwr = bbv;
        __syncthreads();
        bf16x8 af[2], bfr[2];
#pragma unroll
        for (int i = 0; i < 2; i++) af[i] = *(bf16x8*)&As[(wm + i * 16 + lr) * 40 + lq * 8];
#pragma unroll
        for (int j = 0; j < 2; j++) bfr[j] = *(bf16x8*)&Bs[(wn + j * 16 + lr) * 40 + lq * 8];
#pragma unroll
        for (int i = 0; i < 2; i++)
#pragma unroll
            for (int j = 0; j < 2; j++)
                acc[i][j] = __builtin_amdgcn_mfma_f32_16x16x32_bf16(af[i], bfr[j], acc[i][j], 0, 0, 0);
    }
    float* att = ws + OFF_ATT;
    bf16* attB = bp + BATT;
#pragma unroll
    for (int j = 0; j < 2; j++) {
        int gn = n0 + wn + j * 16 + lr;
        float b = out_b[gn];
        float colsum = 0.f;
#pragma unroll
        for (int i = 0; i < 2; i++)
#pragma unroll
            for (int r4 = 0; r4 < 4; r4++) {
                int gm = m0 + wm + i * 16 + lq * 4 + r4;
                float v = acc[i][j][r4] + b;
                att[(size_t)gm * DD + gn] = v;
                attB[(size_t)gm * 512 + gn] = __float2bfloat16(v);
                colsum += v;
            }
        atomicAdd(&ps[wn + j * 16 + lr], colsum);
    }
    __syncthreads();
    if (tid < 64) atomicAdd(&ws[OFF_POOL + n0 + tid], ps[tid]);
}

// triple GEMM A=attB: K2B (0-7) | Q0B (8-15) | H0 fp32 (16-21) + head block (22)
__global__ __launch_bounds__(256) void k_trip(
    const float* __restrict__ in_b, const float* __restrict__ ref_b1,
    const float* __restrict__ icw1, const float* __restrict__ icb1,
    const float* __restrict__ icw2, const float* __restrict__ icb2,
    float* ws, float* out)
{
    bf16* bp = (bf16*)(ws + BF_BASE);
    __shared__ __bf16 As[64 * 40];
    __shared__ __bf16 Bs[64 * 40];
    __shared__ float h1[128];
    __shared__ float lg[MAXI];
    int bx = blockIdx.x, tid = threadIdx.x;
    if (bx == 22) {
        if (blockIdx.y != 0) return;
        int w = tid >> 6, lane = tid & 63;
        const float* pp = ws + OFF_POOL + lane * 8;
        float4 p0 = *(const float4*)pp, p1 = *(const float4*)(pp + 4);
        float p8[8] = {p0.x, p0.y, p0.z, p0.w, p1.x, p1.y, p1.z, p1.w};
        for (int t = 0; t < 32; t++) {
            int row = w * 32 + t;
            const float* wr = icw1 + (size_t)row * DD + lane * 8;
            float4 a = *(const float4*)wr, b = *(const float4*)(wr + 4);
            float d = a.x * p8[0] + a.y * p8[1] + a.z * p8[2] + a.w * p8[3]
                    + b.x * p8[4] + b.y * p8[5] + b.z * p8[6] + b.w * p8[7];
            for (int off = 32; off; off >>= 1) d += __shfl_xor(d, off);
            if (lane == 0) h1[row] = fmaxf(d * (1.0f / NT) + icb1[row], 0.f);
        }
        __syncthreads();
        if (tid < MAXI) {
            float s = icb2[tid];
            for (int j = 0; j < 128; j++) s += icw2[tid * 128 + j] * h1[j];
            lg[tid] = s;
        }
        __syncthreads();
        if (tid == 0) {
            int best = 0; float bv = lg[0];
            for (int m = 1; m < MAXI; m++) if (lg[m] > bv) { bv = lg[m]; best = m; }
            int ni = best + 1;
            for (int i = 0; i < MAXI; i++) out[10 + i] = (i < ni) ? 1.f : 0.f;
        }
        return;
    }
    const __bf16* B; const float* bias; int n0, mode;
    bf16* Cb = nullptr; float* Cf = nullptr;
    if (bx < 8)       { B = (const __bf16*)(bp + BINW) + (size_t)512 * 512; bias = in_b + DD;   Cb = bp + BK2; n0 = bx * 64; mode = 0; }
    else if (bx < 16) { B = (const __bf16*)(bp + BM2);                      bias = ws + OFF_B2; Cb = bp + BQ0; n0 = (bx - 8) * 64; mode = 0; }
    else              { B = (const __bf16*)(bp + BRW1);                     bias = ref_b1;      Cf = ws + OFF_H0; n0 = (bx - 16) * 64; mode = 1; }
    int m0 = blockIdx.y * 64;
    int r = tid >> 2, quad = tid & 3;
    int w = tid >> 6, lane = tid & 63;
    int wm = (w & 1) * 32, wn = (w >> 1) * 32;
    int lr = lane & 15, lq = lane >> 4;
    f32x4 acc[2][2];
#pragma unroll
    for (int i = 0; i < 2; i++)
#pragma unroll
        for (int j = 0; j < 2; j++) acc[i][j] = (f32x4){0.f, 0.f, 0.f, 0.f};

    const __bf16* arow = (const __bf16*)(bp + BATT) + (size_t)(m0 + r) * 512 + quad * 8;
    const __bf16* brow = B + (size_t)(n0 + r) * 512 + quad * 8;
    __bf16* awr = &As[r * 40 + quad * 8];
    __bf16* bwr = &Bs[r * 40 + quad * 8];

    for (int k0 = 0; k0 < DD; k0 += 32) {
        uint4 av = *(const uint4*)(arow + k0);
        uint4 bv = *(const uint4*)(brow + k0);
        __syncthreads();
        *(uint4*)awr = av;
        *(uint4*)bwr = bv;
        __syncthreads();
        bf16x8 af[2], bfr[2];
#pragma unroll
        for (int i = 0; i < 2; i++) af[i] = *(bf16x8*)&As[(wm + i * 16 + lr) * 40 + lq * 8];
#pragma unroll
        for (int j = 0; j < 2; j++) bfr[j] = *(bf16x8*)&Bs[(wn + j * 16 + lr) * 40 + lq * 8];
#pragma unroll
        for (int i = 0; i < 2; i++)
#pragma unroll
            for (int j = 0; j < 2; j++)
                acc[i][j] = __builtin_amdgcn_mfma_f32_16x16x32_bf16(af[i], bfr[j], acc[i][j], 0, 0, 0);
    }
#pragma unroll
    for (int i = 0; i < 2; i++)
#pragma unroll
        for (int r4 = 0; r4 < 4; r4++) {
            int gm = m0 + wm + i * 16 + lq * 4 + r4;
#pragma unroll
            for (int j = 0; j < 2; j++) {
                int gn = n0 + wn + j * 16 + lr;
                float v = acc[i][j][r4] + bias[gn];
                if (mode == 0) Cb[(size_t)gm * 512 + gn] = __float2bfloat16(v);
                else           Cf[(size_t)gm * 384 + gn] = v;
            }
        }
}

// fused: logits = relu(H0+delta)@rw2B^T + b2 in LDS, then softdot -> so/eo
__global__ __launch_bounds__(256) void k_lgs(
    const float* __restrict__ rw1, const float* __restrict__ rb2,
    const float* __restrict__ wp, int l, float* ws)
{
    bf16* bp = (bf16*)(ws + BF_BASE);
    __shared__ float dsh[128];
    __shared__ __bf16 As[64 * 136];
    __shared__ __bf16 Bs[64 * 136];
    __shared__ __bf16 Ls[64 * 208];
    int tid = threadIdx.x;
    int m0 = blockIdx.x * 64;
    int i_int = m0 / NT;
    int nbase = m0 % NT;
    if (blockIdx.x == 0 && tid < 11) ws[OFF_SCAL + SC_DSDE + tid] = 0.f;   // dsde[10] + ticket
    if (tid < 128) {
        float s_i = ws[OFF_SCAL + SC_START + i_int], e_i = ws[OFF_SCAL + SC_END + i_int];
        const float* wr = rw1 + (size_t)(l * 128 + tid) * 514;
        dsh[tid] = s_i * wr[512] + e_i * wr[513];
    }
    __syncthreads();
    int r = tid >> 2, quad = tid & 3;
    {
        const float* arow = ws + OFF_H0 + (size_t)(nbase + r) * 384 + l * 128 + quad * 32;
        __bf16 tmp[32] __attribute__((aligned(16)));
#pragma unroll
        for (int q = 0; q < 16; q++) {
            float2 f = *(const float2*)(arow + 2 * q);
            int jj = quad * 32 + 2 * q;
            tmp[2 * q]     = (__bf16)fmaxf(f.x + dsh[jj], 0.f);
            tmp[2 * q + 1] = (__bf16)fmaxf(f.y + dsh[jj + 1], 0.f);
        }
        __bf16* aw = &As[r * 136 + quad * 32];
#pragma unroll
        for (int q = 0; q < 4; q++) *(bf16x8*)(aw + q * 8) = *(bf16x8*)(tmp + q * 8);
    }
    int w = tid >> 6, lane = tid & 63;
    int wm = (w & 1) * 32, wn = (w >> 1) * 32;
    int lr = lane & 15, lq = lane >> 4;
    const __bf16* rw2b = (const __bf16*)(bp + BRW2) + (size_t)l * 200 * 128;
    for (int nt = 0; nt < 4; nt++) {
        int n0 = nt * 64;
        int gnr = n0 + r;
        uint4 b0 = {0, 0, 0, 0}, b1 = {0, 0, 0, 0}, b2v = {0, 0, 0, 0}, b3 = {0, 0, 0, 0};
        if (gnr < 200) {
            const __bf16* brow = rw2b + (size_t)gnr * 128 + quad * 32;
            b0 = *(const uint4*)brow; b1 = *(const uint4*)(brow + 8);
            b2v = *(const uint4*)(brow + 16); b3 = *(const uint4*)(brow + 24);
        }
        __syncthreads();
        {
            __bf16* bw = &Bs[r * 136 + quad * 32];
            *(uint4*)bw = b0; *(uint4*)(bw + 8) = b1;
            *(uint4*)(bw + 16) = b2v; *(uint4*)(bw + 24) = b3;
        }
        __syncthreads();
        f32x4 acc[2][2];
#pragma unroll
        for (int i = 0; i < 2; i++)
#pragma unroll
            for (int j = 0; j < 2; j++) acc[i][j] = (f32x4){0.f, 0.f, 0.f, 0.f};
#pragma unroll
        for (int kk = 0; kk < 4; kk++) {
            bf16x8 af[2], bfr[2];
#pragma unroll
            for (int i = 0; i < 2; i++) af[i] = *(bf16x8*)&As[(wm + i * 16 + lr) * 136 + kk * 32 + lq * 8];
#pragma unroll
            for (int j = 0; j < 2; j++) bfr[j] = *(bf16x8*)&Bs[(wn + j * 16 + lr) * 136 + kk * 32 + lq * 8];
#pragma unroll
            for (int i = 0; i < 2; i++)
#pragma unroll
                for (int j = 0; j < 2; j++)
                    acc[i][j] = __builtin_amdgcn_mfma_f32_16x16x32_bf16(af[i], bfr[j], acc[i][j], 0, 0, 0);
        }
#pragma unroll
        for (int i = 0; i < 2; i++)
#pragma unroll
            for (int r4 = 0; r4 < 4; r4++) {
                int rl = wm + i * 16 + lq * 4 + r4;
#pragma unroll
                for (int j = 0; j < 2; j++) {
                    int gn = n0 + wn + j * 16 + lr;
                    if (gn < 200) Ls[rl * 208 + gn] = (__bf16)(acc[i][j][r4] + rb2[gn]);
                }
            }
    }
    __syncthreads();
    {
        int rloc = tid >> 2, q = tid & 3;
        int c0 = q * 50;
        const unsigned short* lrow = (const unsigned short*)&Ls[rloc * 208];
        float m = -1e30f;
#pragma unroll
        for (int c = 0; c < 50; c++)
            m = fmaxf(m, __uint_as_float((unsigned)lrow[c0 + c] << 16));
        m = fmaxf(m, __shfl_xor(m, 1));
        float den = 0.f, num = 0.f;
#pragma unroll
        for (int c = 0; c < 50; c++) {
            float p = __expf(__uint_as_float((unsigned)lrow[c0 + c] << 16) - m);
            den += p;
            int wc = c0 + c; if (wc >= NBINS) wc -= NBINS;
            num += p * wp[wc];
        }
        den += __shfl_xor(den, 1);
        num += __shfl_xor(num, 1);
        int n = nbase + rloc;
        if (q == 0)      ws[OFF_SOFF + (size_t)i_int * NT + n] = num / den;
        else if (q == 2) ws[OFF_EOFF + (size_t)i_int * NT + n] = num / den;
    }
}

// P_ks = E0 @ U^T, E0 staged by pure copy, U computed on the fly in B-staging
// grid (8 k-splits, 12 m-tiles, 4 heads) -> disjoint P slices
__global__ __launch_bounds__(256) void k_eg(const bf16* __restrict__ E0, float* ws) {
    int h = blockIdx.z;
    int m0 = blockIdx.y * 128;
    int ks = blockIdx.x;
    const int KCH = NT / 8;
    __shared__ __bf16 As[128 * 40];
    __shared__ __bf16 Bs[16 * 40];
    int tid = threadIdx.x;
    int w = tid >> 6, lane = tid & 63;
    int lr = lane & 15, lq = lane >> 4;
    int r = tid >> 1, half = tid & 1;
    const unsigned short* arow =
        (const unsigned short*)((const __bf16*)E0 + (size_t)h * NT * NT + (size_t)(m0 + r) * NT) + half * 16;
    int wm = w * 32;
    f32x4 acc[2];
    acc[0] = (f32x4){0.f, 0.f, 0.f, 0.f};
    acc[1] = (f32x4){0.f, 0.f, 0.f, 0.f};
    int bc = tid >> 3, bk = tid & 7;
    int valid = (tid < 128) && (bc < 15);
    int ii = bc / 3, tt = bc - ii * 3;
    if (ii > 4) ii = 4;
    float s_i = 0.f, e_i = 0.f;
    if (valid) { s_i = ws[OFF_SCAL + SC_START + ii]; e_i = ws[OFF_SCAL + SC_END + ii]; }
    const float* Ar = ws + OFF_AARR + h * NT;
    const float* Br = ws + OFF_BARR + h * NT;
    const float* fo = ws + (tt == 2 ? OFF_EOFF : OFF_SOFF) + (size_t)ii * NT;

    for (int k0 = ks * KCH; k0 < ks * KCH + KCH; k0 += 32) {
        uint4 a0 = *(const uint4*)(arow + k0);
        uint4 a1 = *(const uint4*)(arow + k0 + 8);
        float bv[4] = {0.f, 0.f, 0.f, 0.f};
        if (valid) {
            float4 a4 = *(const float4*)(Ar + k0 + bk * 4);
            float4 b4 = *(const float4*)(Br + k0 + bk * 4);
            bv[0] = __expf(s_i * a4.x + e_i * b4.x);
            bv[1] = __expf(s_i * a4.y + e_i * b4.y);
            bv[2] = __expf(s_i * a4.z + e_i * b4.z);
            bv[3] = __expf(s_i * a4.w + e_i * b4.w);
            if (tt) {
                float4 f4 = *(const float4*)(fo + k0 + bk * 4);
                bv[0] *= f4.x; bv[1] *= f4.y; bv[2] *= f4.z; bv[3] *= f4.w;
            }
        }
        __syncthreads();
        *(uint4*)&As[r * 40 + half * 16] = a0;
        *(uint4*)&As[r * 40 + half * 16 + 8] = a1;
        if (tid < 128) {
            __bf16* bw = &Bs[bc * 40 + bk * 4];
            bw[0] = (__bf16)bv[0]; bw[1] = (__bf16)bv[1]; bw[2] = (__bf16)bv[2]; bw[3] = (__bf16)bv[3];
        }
        __syncthreads();
        bf16x8 bf0 = *(bf16x8*)&Bs[lr * 40 + lq * 8];
        bf16x8 af0 = *(bf16x8*)&As[(wm + lr) * 40 + lq * 8];
        bf16x8 af1 = *(bf16x8*)&As[(wm + 16 + lr) * 40 + lq * 8];
        acc[0] = __builtin_amdgcn_mfma_f32_16x16x32_bf16(af0, bf0, acc[0], 0, 0, 0);
        acc[1] = __builtin_amdgcn_mfma_f32_16x16x32_bf16(af1, bf0, acc[1], 0, 0, 0);
    }
    float* P = ws + OFF_LG + (size_t)ks * PSLICE;
    if (lr < 15) {
#pragma unroll
        for (int i = 0; i < 2; i++)
#pragma unroll
            for (int r4 = 0; r4 < 4; r4++) {
                int gm = m0 + wm + i * 16 + lq * 4 + r4;
                P[(size_t)(h * NT + gm) * 16 + lr] = acc[i][r4];
            }
    }
}

// sum 8 slices, ratios, reduce; last block applies update (+ writes out on last layer)
__global__ __launch_bounds__(256) void k_fin(float* ws, float* out, int l) {
    __shared__ float part[4][10];
    int tid = threadIdx.x;
    int w = tid >> 6, lane = tid & 63;
    int row = blockIdx.x * 256 + tid;
    float acc[15];
#pragma unroll
    for (int c = 0; c < 15; c++) acc[c] = 0.f;
    for (int ks = 0; ks < 8; ks++) {
        const float* Pr = ws + OFF_LG + (size_t)ks * PSLICE + (size_t)row * 16;
#pragma unroll
        for (int c = 0; c < 15; c++) acc[c] += Pr[c];
    }
    float loc[10];
#pragma unroll
    for (int i = 0; i < MAXI; i++) {
        float den = acc[i * 3];
        loc[i]        = acc[i * 3 + 1] / den;
        loc[MAXI + i] = acc[i * 3 + 2] / den;
    }
#pragma unroll
    for (int c = 0; c < 10; c++)
        for (int off = 32; off; off >>= 1) loc[c] += __shfl_xor(loc[c], off);
    if (lane == 0) {
#pragma unroll
        for (int c = 0; c < 10; c++) part[w][c] = loc[c];
    }
    __syncthreads();
    if (tid < 10) {
        float s = part[0][tid] + part[1][tid] + part[2][tid] + part[3][tid];
        atomicAdd(&ws[OFF_SCAL + SC_DSDE + tid], s);
    }
    __threadfence();
    __syncthreads();
    if (tid == 0) {
        unsigned old = atomicAdd((unsigned*)&ws[OFF_SCAL + SC_CNT], 1u);
        if (old == 23) {
            for (int i = 0; i < MAXI; i++) {
                float ds = atomicAdd(&ws[OFF_SCAL + SC_DSDE + i], 0.f);
                float de = atomicAdd(&ws[OFF_SCAL + SC_DSDE + MAXI + i], 0.f);
                float ns = ws[OFF_SCAL + SC_START + i] + ds * 0.25f;   // 1/H
                float ne = ws[OFF_SCAL + SC_END + i]   + de * 0.25f;
                ws[OFF_SCAL + SC_START + i] = ns;
                ws[OFF_SCAL + SC_END + i]   = ne;
                if (l == NL - 1) { out[2 * i] = ns; out[2 * i + 1] = ne; }
            }
        }
    }
}

// -------------------------------------------------------------------------
extern "C" void kernel_launch(void* const* d_in, const int* in_sizes, int n_in,
                              void* d_out, int out_size, void* d_ws, size_t ws_size,
                              hipStream_t stream) {
    const float* emb    = (const float*)d_in[0];
    const float* tpos   = (const float*)d_in[1];
    const float* W_time = (const float*)d_in[3];
    const float* b_time = (const float*)d_in[4];
    const float* in_w   = (const float*)d_in[5];
    const float* in_b   = (const float*)d_in[6];
    const float* out_w  = (const float*)d_in[7];
    const float* out_b  = (const float*)d_in[8];
    const float* ic_w1  = (const float*)d_in[9];
    const float* ic_b1  = (const float*)d_in[10];
    const float* ic_w2  = (const float*)d_in[11];
    const float* ic_b2  = (const float*)d_in[12];
    const float* ref_w1 = (const float*)d_in[13];
    const float* ref_b1 = (const float*)d_in[14];
    const float* ref_w2 = (const float*)d_in[15];
    const float* ref_b2 = (const float*)d_in[16];
    const float* wp     = (const float*)d_in[17];
    const float* qp_w   = (const float*)d_in[18];
    const float* qp_b   = (const float*)d_in[19];
    float* ws  = (float*)d_ws;
    float* out = (float*)d_out;
    bf16* E = (bf16*)(ws + OFF_E);
    bf16* bp = (bf16*)(ws + BF_BASE);

    // prologue: M2B | uv | pre | weight-to-bf16 converts
    k_misc<<<98, 256, 0, stream>>>(tpos, in_w, in_b, out_w, ref_w1, ref_w2, qp_w, qp_b, ws);

    // qkv (+x fusion) -> QKB bf16, VtB bf16
    k_qkv<<<dim3(24, 24), 256, 0, stream>>>(emb, tpos, W_time, b_time, in_b, ws);
    // E1 = exp(QK^T/sqrt(dh)) + per-tile expsums
    k_score<1><<<dim3(12, 12, NH), 256, 0, stream>>>(
        bp + BQKB, 1024, DHD, bp + BQKB + 512, 1024, DHD, E, ws);
    k_pv<<<dim3(2, NT / 64, NH), 256, 0, stream>>>(E, ws);
    k_oproj<<<dim3(8, 24), 256, 0, stream>>>(out_b, ws);

    // K2B | Q0B | H0 | head
    k_trip<<<dim3(23, 24), 256, 0, stream>>>(in_b, ref_b1, ic_w1, ic_b1, ic_w2, ic_b2, ws, out);

    // E0 = exp(Q0 K2^T / sqrt(dh)) + abc fold (z==4)
    k_score<0><<<dim3(12, 12, 5), 256, 0, stream>>>(
        bp + BQ0, 512, DHD, bp + BK2, 512, DHD, E, ws);

    for (int l = 0; l < NL; l++) {
        k_lgs<<<120, 256, 0, stream>>>(ref_w1, ref_b2 + l * 200, wp, l, ws);
        k_eg<<<dim3(8, NT / 128, NH), 256, 0, stream>>>(E, ws);
        k_fin<<<NH * NT / 256, 256, 0, stream>>>(ws, out, l);
    }
}